// Round 4
// baseline (615.391 us; speedup 1.0000x reference)
//
#include <hip/hip_runtime.h>
#include <hip/hip_bf16.h>
#include <string.h>

// KanGNN. Inputs f32 + int32, output f32.
// R14 = R13 with compile fix (__builtin_bit_cast -> memcpy; __hip_bfloat162
// is not trivially copyable on this ROCm).
// R13: kan_mfma LDS-free. Root cause of the LDS exchange: lane (m_n,quad)
// built inputs i=[4q,4q+4) but consumed a different (i,k) slice. Fix: permute
// the K-axis element mapping (applied identically to A-build and B-repack —
// contraction is invariant) so each lane builds EXACTLY its own A-fragment
// words in registers -> no LDS, no fences, no barriers, no bank conflicts.
// Build pack via v_cvt_pk_bf16_f32 (RNE, same bits as the +0x7fff trick).
// Numerics: MFMA K-grouping reorder -> f32 sum-order noise only (~1e-6).
// R11: 2-level binned counting-sort CSR build (unchanged).

#define N_NODES 100000
#define IN_FEAT 128
#define HID 64
#define OUT_FEAT 40
#define NGRID 8
#define N_EDGES 1600000
#define NELEM (N_NODES * HID)

#define NB 98            // buckets: row >> 10
#define CAP 18432        // per-bucket capacity (mean 16384, sigma ~127)
#define BCHUNK 4096      // edges per bin block
#define BIN_BLOCKS ((N_EDGES + BCHUNK - 1) / BCHUNK)   // 391

using short8 = __attribute__((ext_vector_type(8))) short;
using floatx4 = __attribute__((ext_vector_type(4))) float;
using uintx4 = __attribute__((ext_vector_type(4))) unsigned;

// f32 -> bf16 RNE, packed pair (lo = c, hi = s) — bit-manip form (repack
// path; keeps B coefficient rounding byte-identical to R11/R12)
__device__ __forceinline__ unsigned pack_bf16x2(float c, float s) {
  unsigned uc = __float_as_uint(c);
  unsigned us = __float_as_uint(s);
  uc += 0x7fffu + ((uc >> 16) & 1u);
  us += 0x7fffu + ((us >> 16) & 1u);
  return (uc >> 16) | (us & 0xffff0000u);
}

// same RNE conversion via v_cvt_pk_bf16_f32 (1 instr instead of ~11)
__device__ __forceinline__ unsigned cvtpk_bf16x2(float c, float s) {
  __hip_bfloat162 p = __float22bfloat162_rn(make_float2(c, s));
  unsigned r;
  memcpy(&r, &p, 4);
  return r;
}

// ---------------------------------------------------------------- lin_in
__global__ __launch_bounds__(256) void lin_in_kernel(
    const float* __restrict__ x, const float* __restrict__ W,
    const float* __restrict__ b, float* __restrict__ h) {
  __shared__ __align__(16) float xs[16 * IN_FEAT];   // 8 KB
  int t = threadIdx.x;
  int nb = blockIdx.x;
  const float4* xsrc = (const float4*)(x + (size_t)nb * 16 * IN_FEAT);
  float4* xd = (float4*)xs;
  xd[t] = xsrc[t];
  xd[t + 256] = xsrc[t + 256];
  __syncthreads();
  int lane = t & 63, wv = t >> 6;
  float bj = b[lane];
  float a0 = bj, a1 = bj, a2 = bj, a3 = bj;
  const float* xr = xs + wv * 4 * IN_FEAT;
  const float* Wj = W + lane;
#pragma unroll 4
  for (int i4 = 0; i4 < 32; i4++) {
    float4 x0 = *(const float4*)(xr + 0 * IN_FEAT + i4 * 4);
    float4 x1 = *(const float4*)(xr + 1 * IN_FEAT + i4 * 4);
    float4 x2 = *(const float4*)(xr + 2 * IN_FEAT + i4 * 4);
    float4 x3 = *(const float4*)(xr + 3 * IN_FEAT + i4 * 4);
    float w0 = Wj[(i4 * 4 + 0) * HID];
    float w1 = Wj[(i4 * 4 + 1) * HID];
    float w2 = Wj[(i4 * 4 + 2) * HID];
    float w3 = Wj[(i4 * 4 + 3) * HID];
    a0 = fmaf(x0.x, w0, a0); a0 = fmaf(x0.y, w1, a0); a0 = fmaf(x0.z, w2, a0); a0 = fmaf(x0.w, w3, a0);
    a1 = fmaf(x1.x, w0, a1); a1 = fmaf(x1.y, w1, a1); a1 = fmaf(x1.z, w2, a1); a1 = fmaf(x1.w, w3, a1);
    a2 = fmaf(x2.x, w0, a2); a2 = fmaf(x2.y, w1, a2); a2 = fmaf(x2.z, w2, a2); a2 = fmaf(x2.w, w3, a2);
    a3 = fmaf(x3.x, w0, a3); a3 = fmaf(x3.y, w1, a3); a3 = fmaf(x3.z, w2, a3); a3 = fmaf(x3.w, w3, a3);
  }
  size_t nbase = (size_t)nb * 16 + wv * 4;
  h[(nbase + 0) * HID + lane] = a0;
  h[(nbase + 1) * HID + lane] = a1;
  h[(nbase + 2) * HID + lane] = a2;
  h[(nbase + 3) * HID + lane] = a3;
}

// ---------------------------------------------------------------- CSR build (R11)
__global__ __launch_bounds__(128) void binit_kernel(int* __restrict__ btail) {
  int t = threadIdx.x;
  if (t < NB) btail[t] = t * CAP;
}

// Pass 1: coarse-bucket counting sort.
__global__ __launch_bounds__(256) void bin_kernel(
    const int* __restrict__ row, const int* __restrict__ col,
    const float* __restrict__ w, int* __restrict__ btail,
    uint2* __restrict__ pack1) {
  __shared__ __align__(16) uint2 stage[BCHUNK];   // 32 KB
  __shared__ int bcnt[NB];
  __shared__ int lbase[NB];
  __shared__ int gbase[NB];
  __shared__ int lcur[NB];
  __shared__ int sc[128];
  int t = threadIdx.x;
  int e0 = blockIdx.x * BCHUNK;
  if (t < NB) bcnt[t] = 0;
  __syncthreads();
  int rloc[16];
#pragma unroll
  for (int q = 0; q < 16; q++) {
    int e = e0 + q * 256 + t;
    int r = (e < N_EDGES) ? row[e] : -1;
    rloc[q] = r;
    if (r >= 0) atomicAdd(&bcnt[r >> 10], 1);
  }
  __syncthreads();
  int c = (t < NB) ? bcnt[t] : 0;
  if (t < 128) sc[t] = c;
  __syncthreads();
  int v = c;
#pragma unroll
  for (int off = 1; off < 128; off <<= 1) {
    int add = (t >= off && t < 128) ? sc[t - off] : 0;
    __syncthreads();
    if (t < 128) sc[t] = v = v + add;
    __syncthreads();
  }
  if (t < NB) {
    lbase[t] = v - c;
    lcur[t] = v - c;
    gbase[t] = atomicAdd(&btail[t], c);
  }
  __syncthreads();
#pragma unroll
  for (int q = 0; q < 16; q++) {
    int e = e0 + q * 256 + t;
    int r = rloc[q];
    if (r >= 0) {
      int p = atomicAdd(&lcur[r >> 10], 1);
      unsigned key = ((unsigned)(r & 1023) << 17) | (unsigned)col[e];
      stage[p] = make_uint2(key, __float_as_uint(w[e]));
    }
  }
  __syncthreads();
  int wv = t >> 6, lane = t & 63;
  for (int b = wv; b < NB; b += 4) {
    int len = bcnt[b], src = lbase[b];
    uint2* dst = pack1 + (size_t)gbase[b];
    for (int i = lane; i < len; i += 64)
      dst[i] = stage[src + i];
  }
}

// Pass 2: one block per bucket -> rowptr + exact scatter.
__global__ __launch_bounds__(256) void bucket_finalize_kernel(
    const int* __restrict__ btail, const uint2* __restrict__ pack1,
    int* __restrict__ rowptr, uint2* __restrict__ pack2) {
  __shared__ int rcnt[1024];
  __shared__ int sc[256];
  __shared__ int binfo[2];
  int b = blockIdx.x, t = threadIdx.x;
  if (t < NB) sc[t] = btail[t] - t * CAP;   // per-bucket counts
  rcnt[t] = 0; rcnt[t + 256] = 0; rcnt[t + 512] = 0; rcnt[t + 768] = 0;
  __syncthreads();
  if (t == 0) {
    int base = 0;
    for (int i = 0; i < b; i++) base += sc[i];
    binfo[0] = base;
    binfo[1] = sc[b];
  }
  __syncthreads();
  int base = binfo[0], len = binfo[1];
  const uint2* rec = pack1 + (size_t)b * CAP;
  for (int i = t; i < len; i += 256)
    atomicAdd(&rcnt[rec[i].x >> 17], 1);
  __syncthreads();
  int c0 = rcnt[4 * t], c1 = rcnt[4 * t + 1], c2 = rcnt[4 * t + 2], c3 = rcnt[4 * t + 3];
  int s4 = c0 + c1 + c2 + c3;
  sc[t] = s4;
  __syncthreads();
  int v = s4;
#pragma unroll
  for (int off = 1; off < 256; off <<= 1) {
    int add = (t >= off) ? sc[t - off] : 0;
    __syncthreads();
    sc[t] = v = v + add;
    __syncthreads();
  }
  int excl = v - s4;
  int p0 = base + excl;
  int p1 = p0 + c0, p2 = p1 + c1, p3 = p2 + c2;
  int r0 = (b << 10) + 4 * t;
  if (r0 + 0 < N_NODES) rowptr[r0 + 0] = p0;
  if (r0 + 1 < N_NODES) rowptr[r0 + 1] = p1;
  if (r0 + 2 < N_NODES) rowptr[r0 + 2] = p2;
  if (r0 + 3 < N_NODES) rowptr[r0 + 3] = p3;
  rcnt[4 * t] = p0; rcnt[4 * t + 1] = p1; rcnt[4 * t + 2] = p2; rcnt[4 * t + 3] = p3;
  __syncthreads();
  for (int i = t; i < len; i += 256) {
    uint2 p = rec[i];
    int pos = atomicAdd(&rcnt[p.x >> 17], 1);
    pack2[pos] = make_uint2(p.x & 0x1FFFFu, p.y);
  }
  if (b == NB - 1 && t == 0) rowptr[N_NODES] = N_EDGES;
}

// ---------------------------------------------------------------- spmm (CSR, atomic-free)
__global__ __launch_bounds__(256) void spmm_csr_kernel(
    const int* __restrict__ rowptr, const uint2* __restrict__ pack,
    const float* __restrict__ h, float* __restrict__ acc) {
  int wv = threadIdx.x >> 6, lane = threadIdx.x & 63;
  int n = blockIdx.x * 4 + wv;
  int beg = rowptr[n], end = rowptr[n + 1];
  int slot = lane >> 4, f4 = lane & 15;
  const float4* h4 = (const float4*)h;
  float4 v = make_float4(0.f, 0.f, 0.f, 0.f);
  for (int e = beg; e < end; e += 4) {
    int idx = e + slot;
    int col = 0;
    float wt = 0.f;
    if (idx < end) {
      uint2 p = pack[idx];
      col = (int)p.x;
      wt = __uint_as_float(p.y);
    }
    float4 hv = h4[(size_t)col * 16 + f4];
    v.x = fmaf(wt, hv.x, v.x);
    v.y = fmaf(wt, hv.y, v.y);
    v.z = fmaf(wt, hv.z, v.z);
    v.w = fmaf(wt, hv.w, v.w);
  }
#pragma unroll
  for (int off = 16; off < 64; off <<= 1) {
    v.x += __shfl_xor(v.x, off);
    v.y += __shfl_xor(v.y, off);
    v.z += __shfl_xor(v.z, off);
    v.w += __shfl_xor(v.w, off);
  }
  if (slot == 0)
    ((float4*)acc)[(size_t)n * 16 + f4] = v;
}

// ---------------------------------------------------------------- repack
// R13: permuted placement so kan's A-fragments are lane-local.
// Word position (j, w): w = ch*128 + wc, wc = 16*ks + 4*quad + jj,
//   r = ks>>1, km1 = ((ks&1)<<2)|jj, i = ch*16 + 4*quad + r
// holds (C0[j][i][km1], C1[j][i][km1]). Same pack_bf16x2 -> same rounding.
__global__ __launch_bounds__(256) void repack_kernel(
    const float* __restrict__ coeffs, unsigned* __restrict__ Brep) {
  int idx = blockIdx.x * 256 + threadIdx.x;   // 32768 words
  int j = idx >> 9, w = idx & 511;
  int ch = w >> 7, wc = w & 127;
  int ks = wc >> 4, off = wc & 15;
  int quad = off >> 2, jj = off & 3;
  int r = ks >> 1, km1 = ((ks & 1) << 2) | jj;
  int i = ch * 16 + quad * 4 + r;
  int ws = i * 8 + km1;
  float c0 = coeffs[(size_t)j * 512 + ws];
  float c1 = coeffs[32768 + (size_t)j * 512 + ws];
  Brep[idx] = pack_bf16x2(c0, c1);
}

// ---------------------------------------------------------------- KAN via MFMA (LDS-free)
// Lane (m_n, quad) builds inputs i = ch*16 + 4*quad + r (r=0..3), k=1..8,
// directly into its own A-fragment registers:
//   afr[2r]   = words for ks=2r   (k=1..4)
//   afr[2r+1] = words for ks=2r+1 (k=5..8)
// B is repacked to match (see repack_kernel). No LDS, no fences, no barriers.
__global__ __launch_bounds__(256, 4) void kan_mfma_kernel(
    const float* __restrict__ s, const unsigned short* __restrict__ Brep,
    float* __restrict__ out) {
  int t = threadIdx.x;
  int lane = t & 63;
  int wv = t >> 6;
  int nb = blockIdx.x;

  int m_n = lane & 15;            // A row within 16x16 tile
  int quad = lane >> 4;           // k-quad of the MFMA fragment
  int node_sub = wv * 16 + m_n;
  int n_row = nb * 64 + node_sub;
  bool rvalid = (n_row < N_NODES);

  // per-lane B base: short8 index = (jt*16+m_n)*128 + ch*32 + ks*4 + quad
  const short8* B8 = reinterpret_cast<const short8*>(Brep);
  const short8* Bl = B8 + (size_t)m_n * 128 + quad;

  // prefetch all 4 chunks' s-vectors (i = ch*16 + quad*4 + r)
  float4 sv[4];
#pragma unroll
  for (int ch = 0; ch < 4; ch++) {
    sv[ch] = rvalid
      ? *reinterpret_cast<const float4*>(s + (size_t)n_row * HID + ch * 16 + quad * 4)
      : make_float4(0.f, 0.f, 0.f, 0.f);
  }

  floatx4 acc[4];
#pragma unroll
  for (int jt = 0; jt < 4; jt++) acc[jt] = (floatx4){0.f, 0.f, 0.f, 0.f};

#pragma unroll
  for (int ch = 0; ch < 4; ch++) {
    const int cb = ch * 32;
    short8 afr[8];
    float ss[4] = {sv[ch].x, sv[ch].y, sv[ch].z, sv[ch].w};
#pragma unroll
    for (int r = 0; r < 4; r++) {
      float s1, c1;
      __sincosf(ss[r], &s1, &c1);
      float ck = c1, sk = s1;
      unsigned wbuf[8];
#pragma unroll
      for (int km1 = 0; km1 < 8; km1++) {
        wbuf[km1] = cvtpk_bf16x2(ck, sk);
        float cn = fmaf(ck, c1, -sk * s1);
        float sn = fmaf(sk, c1, ck * s1);
        ck = cn; sk = sn;
      }
      uintx4 lo = (uintx4){wbuf[0], wbuf[1], wbuf[2], wbuf[3]};
      uintx4 hi = (uintx4){wbuf[4], wbuf[5], wbuf[6], wbuf[7]};
      memcpy(&afr[2 * r], &lo, 16);
      memcpy(&afr[2 * r + 1], &hi, 16);
    }
#pragma unroll
    for (int ks = 0; ks < 8; ks++) {
      short8 af = afr[ks];
      acc[0] = __builtin_amdgcn_mfma_f32_16x16x32_bf16(af, Bl[0 * 2048 + cb + ks * 4], acc[0], 0, 0, 0);
      acc[1] = __builtin_amdgcn_mfma_f32_16x16x32_bf16(af, Bl[1 * 2048 + cb + ks * 4], acc[1], 0, 0, 0);
      acc[2] = __builtin_amdgcn_mfma_f32_16x16x32_bf16(af, Bl[2 * 2048 + cb + ks * 4], acc[2], 0, 0, 0);
      acc[3] = __builtin_amdgcn_mfma_f32_16x16x32_bf16(af, Bl[3 * 2048 + cb + ks * 4], acc[3], 0, 0, 0);
    }
  }

  // ---- epilogue: D col=lane&15 (j), row=quad*4+reg (node) ----
#pragma unroll
  for (int jt = 0; jt < 4; jt++) {
#pragma unroll
    for (int reg = 0; reg < 4; reg++) {
      int node = nb * 64 + wv * 16 + quad * 4 + reg;
      if (node < N_NODES)
        out[(size_t)node * HID + jt * 16 + m_n] = acc[jt][reg];
    }
  }
}

// ---------------------------------------------------------------- final linear + log_softmax
__global__ __launch_bounds__(256) void final_kernel(
    const float* __restrict__ h, const float* __restrict__ Wout,
    float* __restrict__ out) {
  __shared__ float Ws[HID * OUT_FEAT];
  __shared__ float hs[4][HID];
  int t = threadIdx.x;
  for (int idx = t; idx < HID * OUT_FEAT; idx += 256)
    Ws[idx] = Wout[idx];
  int wave = t >> 6, lane = t & 63;
  int n = blockIdx.x * 4 + wave;
  hs[wave][lane] = h[(size_t)n * HID + lane];
  __syncthreads();
  float d = 0.f;
  if (lane < OUT_FEAT) {
#pragma unroll 8
    for (int i = 0; i < HID; i++)
      d = fmaf(hs[wave][i], Ws[i * OUT_FEAT + lane], d);
  }
  float m = (lane < OUT_FEAT) ? d : -1e30f;
#pragma unroll
  for (int off = 32; off; off >>= 1) m = fmaxf(m, __shfl_xor(m, off));
  float ex = (lane < OUT_FEAT) ? expf(d - m) : 0.f;
  float ssum = ex;
#pragma unroll
  for (int off = 32; off; off >>= 1) ssum += __shfl_xor(ssum, off);
  float lse = m + logf(ssum);
  if (lane < OUT_FEAT)
    out[(size_t)n * OUT_FEAT + lane] = d - lse;
}

// ---------------------------------------------------------------- launch
extern "C" void kernel_launch(void* const* d_in, const int* in_sizes, int n_in,
                              void* d_out, int out_size, void* d_ws, size_t ws_size,
                              hipStream_t stream) {
  (void)in_sizes; (void)n_in; (void)out_size; (void)ws_size;
  const float* x    = (const float*)d_in[0];
  const int*   erow = (const int*)d_in[1];
  const int*   ecol = (const int*)d_in[2];
  const float* ew   = (const float*)d_in[3];
  const float* W_in = (const float*)d_in[4];
  const float* b_in = (const float*)d_in[5];
  const float* c1   = (const float*)d_in[6];
  const float* c2   = (const float*)d_in[7];
  const float* Wout = (const float*)d_in[8];
  float* out = (float*)d_out;

  float* h   = (float*)d_ws;
  float* acc = h + NELEM;

  // x buffer (12.8M words, 51.2MB) is consumed by lin_in, then reused:
  unsigned* xw     = (unsigned*)(void*)x;
  unsigned* Brep1  = xw;                     // [0, 32768)
  unsigned* Brep2  = xw + 32768;             // [32768, 65536)
  int*      btail  = (int*)(xw + 65536);     // 98
  int*      rowptr = (int*)(xw + 66048);     // 100001
  uint2*    pack1  = (uint2*)(xw + 262144);  // 98*18432 uint2 (ends 3,874,816)
  uint2*    pack2  = (uint2*)(xw + 3932160); // 1.6M uint2 (ends 7,132,160)

  lin_in_kernel<<<N_NODES / 16, 256, 0, stream>>>(x, W_in, b_in, h);

  repack_kernel<<<128, 256, 0, stream>>>(c1, Brep1);
  repack_kernel<<<128, 256, 0, stream>>>(c2, Brep2);

  binit_kernel<<<1, 128, 0, stream>>>(btail);
  bin_kernel<<<BIN_BLOCKS, 256, 0, stream>>>(erow, ecol, ew, btail, pack1);
  bucket_finalize_kernel<<<NB, 256, 0, stream>>>(btail, pack1, rowptr, pack2);

  spmm_csr_kernel<<<N_NODES / 4, 256, 0, stream>>>(rowptr, pack2, h, acc);
  kan_mfma_kernel<<<(N_NODES + 63) / 64, 256, 0, stream>>>(acc, (const unsigned short*)Brep1, h);

  spmm_csr_kernel<<<N_NODES / 4, 256, 0, stream>>>(rowptr, pack2, h, acc);
  kan_mfma_kernel<<<(N_NODES + 63) / 64, 256, 0, stream>>>(acc, (const unsigned short*)Brep2, h);

  final_kernel<<<N_NODES / 4, 256, 0, stream>>>(h, Wout, out);
}

// Round 5
// 542.309 us; speedup vs baseline: 1.1348x; 1.1348x over previous
//
#include <hip/hip_runtime.h>
#include <hip/hip_bf16.h>
#include <string.h>

// KanGNN. Inputs f32 + int32, output f32.
// R15: kan_mfma B through LDS. R14 (LDS-free) showed every wave streams the
// ENTIRE 128KB Brep through L2/L3 (6252 waves x 128KB = 800MB/dispatch);
// the concurrent 25.6MB s-stream thrashes the 4MB per-XCD L2, so B re-reads
// hit L3 (~8-10TB/s) -> ~100us floor. Fix: stage each 32KB ch-slice in LDS
// once per block (4x traffic cut), reg-staged bulk loads for ch+1 issued
// before ch's build; MFMA feeds from conflict-free ds_read_b128 (each
// (jt,ks) read = one contiguous 1KB block; Brep re-linearized in repack to
// make both staging and reads contiguous). Fragment values, build math and
// MFMA order bit-identical to R14.
// R13/R14: lane-local A build (K-axis permutation applied to A+B equally).
// R11: 2-level binned counting-sort CSR build (unchanged).

#define N_NODES 100000
#define IN_FEAT 128
#define HID 64
#define OUT_FEAT 40
#define NGRID 8
#define N_EDGES 1600000
#define NELEM (N_NODES * HID)

#define NB 98            // buckets: row >> 10
#define CAP 18432        // per-bucket capacity (mean 16384, sigma ~127)
#define BCHUNK 4096      // edges per bin block
#define BIN_BLOCKS ((N_EDGES + BCHUNK - 1) / BCHUNK)   // 391

using short8 = __attribute__((ext_vector_type(8))) short;
using floatx4 = __attribute__((ext_vector_type(4))) float;
using uintx4 = __attribute__((ext_vector_type(4))) unsigned;

// f32 -> bf16 RNE, packed pair (lo = c, hi = s) — bit-manip form (repack
// path; keeps B coefficient rounding byte-identical to R11..R14)
__device__ __forceinline__ unsigned pack_bf16x2(float c, float s) {
  unsigned uc = __float_as_uint(c);
  unsigned us = __float_as_uint(s);
  uc += 0x7fffu + ((uc >> 16) & 1u);
  us += 0x7fffu + ((us >> 16) & 1u);
  return (uc >> 16) | (us & 0xffff0000u);
}

// same RNE conversion via v_cvt_pk_bf16_f32 (1 instr instead of ~11)
__device__ __forceinline__ unsigned cvtpk_bf16x2(float c, float s) {
  __hip_bfloat162 p = __float22bfloat162_rn(make_float2(c, s));
  unsigned r;
  memcpy(&r, &p, 4);
  return r;
}

// ---------------------------------------------------------------- lin_in
__global__ __launch_bounds__(256) void lin_in_kernel(
    const float* __restrict__ x, const float* __restrict__ W,
    const float* __restrict__ b, float* __restrict__ h) {
  __shared__ __align__(16) float xs[16 * IN_FEAT];   // 8 KB
  int t = threadIdx.x;
  int nb = blockIdx.x;
  const float4* xsrc = (const float4*)(x + (size_t)nb * 16 * IN_FEAT);
  float4* xd = (float4*)xs;
  xd[t] = xsrc[t];
  xd[t + 256] = xsrc[t + 256];
  __syncthreads();
  int lane = t & 63, wv = t >> 6;
  float bj = b[lane];
  float a0 = bj, a1 = bj, a2 = bj, a3 = bj;
  const float* xr = xs + wv * 4 * IN_FEAT;
  const float* Wj = W + lane;
#pragma unroll 4
  for (int i4 = 0; i4 < 32; i4++) {
    float4 x0 = *(const float4*)(xr + 0 * IN_FEAT + i4 * 4);
    float4 x1 = *(const float4*)(xr + 1 * IN_FEAT + i4 * 4);
    float4 x2 = *(const float4*)(xr + 2 * IN_FEAT + i4 * 4);
    float4 x3 = *(const float4*)(xr + 3 * IN_FEAT + i4 * 4);
    float w0 = Wj[(i4 * 4 + 0) * HID];
    float w1 = Wj[(i4 * 4 + 1) * HID];
    float w2 = Wj[(i4 * 4 + 2) * HID];
    float w3 = Wj[(i4 * 4 + 3) * HID];
    a0 = fmaf(x0.x, w0, a0); a0 = fmaf(x0.y, w1, a0); a0 = fmaf(x0.z, w2, a0); a0 = fmaf(x0.w, w3, a0);
    a1 = fmaf(x1.x, w0, a1); a1 = fmaf(x1.y, w1, a1); a1 = fmaf(x1.z, w2, a1); a1 = fmaf(x1.w, w3, a1);
    a2 = fmaf(x2.x, w0, a2); a2 = fmaf(x2.y, w1, a2); a2 = fmaf(x2.z, w2, a2); a2 = fmaf(x2.w, w3, a2);
    a3 = fmaf(x3.x, w0, a3); a3 = fmaf(x3.y, w1, a3); a3 = fmaf(x3.z, w2, a3); a3 = fmaf(x3.w, w3, a3);
  }
  size_t nbase = (size_t)nb * 16 + wv * 4;
  h[(nbase + 0) * HID + lane] = a0;
  h[(nbase + 1) * HID + lane] = a1;
  h[(nbase + 2) * HID + lane] = a2;
  h[(nbase + 3) * HID + lane] = a3;
}

// ---------------------------------------------------------------- CSR build (R11)
__global__ __launch_bounds__(128) void binit_kernel(int* __restrict__ btail) {
  int t = threadIdx.x;
  if (t < NB) btail[t] = t * CAP;
}

// Pass 1: coarse-bucket counting sort.
__global__ __launch_bounds__(256) void bin_kernel(
    const int* __restrict__ row, const int* __restrict__ col,
    const float* __restrict__ w, int* __restrict__ btail,
    uint2* __restrict__ pack1) {
  __shared__ __align__(16) uint2 stage[BCHUNK];   // 32 KB
  __shared__ int bcnt[NB];
  __shared__ int lbase[NB];
  __shared__ int gbase[NB];
  __shared__ int lcur[NB];
  __shared__ int sc[128];
  int t = threadIdx.x;
  int e0 = blockIdx.x * BCHUNK;
  if (t < NB) bcnt[t] = 0;
  __syncthreads();
  int rloc[16];
#pragma unroll
  for (int q = 0; q < 16; q++) {
    int e = e0 + q * 256 + t;
    int r = (e < N_EDGES) ? row[e] : -1;
    rloc[q] = r;
    if (r >= 0) atomicAdd(&bcnt[r >> 10], 1);
  }
  __syncthreads();
  int c = (t < NB) ? bcnt[t] : 0;
  if (t < 128) sc[t] = c;
  __syncthreads();
  int v = c;
#pragma unroll
  for (int off = 1; off < 128; off <<= 1) {
    int add = (t >= off && t < 128) ? sc[t - off] : 0;
    __syncthreads();
    if (t < 128) sc[t] = v = v + add;
    __syncthreads();
  }
  if (t < NB) {
    lbase[t] = v - c;
    lcur[t] = v - c;
    gbase[t] = atomicAdd(&btail[t], c);
  }
  __syncthreads();
#pragma unroll
  for (int q = 0; q < 16; q++) {
    int e = e0 + q * 256 + t;
    int r = rloc[q];
    if (r >= 0) {
      int p = atomicAdd(&lcur[r >> 10], 1);
      unsigned key = ((unsigned)(r & 1023) << 17) | (unsigned)col[e];
      stage[p] = make_uint2(key, __float_as_uint(w[e]));
    }
  }
  __syncthreads();
  int wv = t >> 6, lane = t & 63;
  for (int b = wv; b < NB; b += 4) {
    int len = bcnt[b], src = lbase[b];
    uint2* dst = pack1 + (size_t)gbase[b];
    for (int i = lane; i < len; i += 64)
      dst[i] = stage[src + i];
  }
}

// Pass 2: one block per bucket -> rowptr + exact scatter.
__global__ __launch_bounds__(256) void bucket_finalize_kernel(
    const int* __restrict__ btail, const uint2* __restrict__ pack1,
    int* __restrict__ rowptr, uint2* __restrict__ pack2) {
  __shared__ int rcnt[1024];
  __shared__ int sc[256];
  __shared__ int binfo[2];
  int b = blockIdx.x, t = threadIdx.x;
  if (t < NB) sc[t] = btail[t] - t * CAP;   // per-bucket counts
  rcnt[t] = 0; rcnt[t + 256] = 0; rcnt[t + 512] = 0; rcnt[t + 768] = 0;
  __syncthreads();
  if (t == 0) {
    int base = 0;
    for (int i = 0; i < b; i++) base += sc[i];
    binfo[0] = base;
    binfo[1] = sc[b];
  }
  __syncthreads();
  int base = binfo[0], len = binfo[1];
  const uint2* rec = pack1 + (size_t)b * CAP;
  for (int i = t; i < len; i += 256)
    atomicAdd(&rcnt[rec[i].x >> 17], 1);
  __syncthreads();
  int c0 = rcnt[4 * t], c1 = rcnt[4 * t + 1], c2 = rcnt[4 * t + 2], c3 = rcnt[4 * t + 3];
  int s4 = c0 + c1 + c2 + c3;
  sc[t] = s4;
  __syncthreads();
  int v = s4;
#pragma unroll
  for (int off = 1; off < 256; off <<= 1) {
    int add = (t >= off) ? sc[t - off] : 0;
    __syncthreads();
    sc[t] = v = v + add;
    __syncthreads();
  }
  int excl = v - s4;
  int p0 = base + excl;
  int p1 = p0 + c0, p2 = p1 + c1, p3 = p2 + c2;
  int r0 = (b << 10) + 4 * t;
  if (r0 + 0 < N_NODES) rowptr[r0 + 0] = p0;
  if (r0 + 1 < N_NODES) rowptr[r0 + 1] = p1;
  if (r0 + 2 < N_NODES) rowptr[r0 + 2] = p2;
  if (r0 + 3 < N_NODES) rowptr[r0 + 3] = p3;
  rcnt[4 * t] = p0; rcnt[4 * t + 1] = p1; rcnt[4 * t + 2] = p2; rcnt[4 * t + 3] = p3;
  __syncthreads();
  for (int i = t; i < len; i += 256) {
    uint2 p = rec[i];
    int pos = atomicAdd(&rcnt[p.x >> 17], 1);
    pack2[pos] = make_uint2(p.x & 0x1FFFFu, p.y);
  }
  if (b == NB - 1 && t == 0) rowptr[N_NODES] = N_EDGES;
}

// ---------------------------------------------------------------- spmm (CSR, atomic-free)
__global__ __launch_bounds__(256) void spmm_csr_kernel(
    const int* __restrict__ rowptr, const uint2* __restrict__ pack,
    const float* __restrict__ h, float* __restrict__ acc) {
  int wv = threadIdx.x >> 6, lane = threadIdx.x & 63;
  int n = blockIdx.x * 4 + wv;
  int beg = rowptr[n], end = rowptr[n + 1];
  int slot = lane >> 4, f4 = lane & 15;
  const float4* h4 = (const float4*)h;
  float4 v = make_float4(0.f, 0.f, 0.f, 0.f);
  for (int e = beg; e < end; e += 4) {
    int idx = e + slot;
    int col = 0;
    float wt = 0.f;
    if (idx < end) {
      uint2 p = pack[idx];
      col = (int)p.x;
      wt = __uint_as_float(p.y);
    }
    float4 hv = h4[(size_t)col * 16 + f4];
    v.x = fmaf(wt, hv.x, v.x);
    v.y = fmaf(wt, hv.y, v.y);
    v.z = fmaf(wt, hv.z, v.z);
    v.w = fmaf(wt, hv.w, v.w);
  }
#pragma unroll
  for (int off = 16; off < 64; off <<= 1) {
    v.x += __shfl_xor(v.x, off);
    v.y += __shfl_xor(v.y, off);
    v.z += __shfl_xor(v.z, off);
    v.w += __shfl_xor(v.w, off);
  }
  if (slot == 0)
    ((float4*)acc)[(size_t)n * 16 + f4] = v;
}

// ---------------------------------------------------------------- repack
// R15 layout: word idx = ch*8192 + (jt*8+ks)*256 + (m_n*4+quad)*4 + jj.
// -> staging is a straight linear copy per 32KB ch-slice, and each (jt,ks)
// ds_read_b128 covers one contiguous 1KB block (conflict-free).
// Fragment content (which C0/C1 element in which word) identical to R14:
//   r = ks>>1, km1 = ((ks&1)<<2)|jj, i = ch*16 + 4*quad + r, j = jt*16+m_n.
__global__ __launch_bounds__(256) void repack_kernel(
    const float* __restrict__ coeffs, unsigned* __restrict__ Brep) {
  int idx = blockIdx.x * 256 + threadIdx.x;   // 32768 words
  int ch = idx >> 13;
  int rem = idx & 8191;
  int jtks = rem >> 8;          // 0..31
  int jt = jtks >> 3, ks = jtks & 7;
  int rem2 = rem & 255;
  int mq = rem2 >> 2;           // 0..63 = m_n*4 + quad
  int m_n = mq >> 2, quad = mq & 3;
  int jj = rem2 & 3;
  int j = jt * 16 + m_n;
  int r = ks >> 1, km1 = ((ks & 1) << 2) | jj;
  int i = ch * 16 + quad * 4 + r;
  int ws = i * 8 + km1;
  float c0 = coeffs[(size_t)j * 512 + ws];
  float c1 = coeffs[32768 + (size_t)j * 512 + ws];
  Brep[idx] = pack_bf16x2(c0, c1);
}

// ---------------------------------------------------------------- KAN via MFMA (B in LDS)
// Per block: 4 waves x 16 nodes. B ch-slice (32KB) staged in LDS once per
// block (was: every wave re-read all 128KB from L2/L3). Stage loads for
// ch+1 issued at the top of ch so HBM/L3 latency hides under build+MFMA.
// A build lane-local in registers (R13 mapping), bit-identical math.
__global__ __launch_bounds__(256, 4) void kan_mfma_kernel(
    const float* __restrict__ s, const unsigned* __restrict__ Brep,
    float* __restrict__ out) {
  __shared__ __align__(16) unsigned Bs[8192];   // 32 KB
  int t = threadIdx.x;
  int lane = t & 63;
  int wv = t >> 6;
  int nb = blockIdx.x;

  int m_n = lane & 15;            // A row within 16x16 tile
  int quad = lane >> 4;           // k-quad of the MFMA fragment
  int node_sub = wv * 16 + m_n;
  int n_row = nb * 64 + node_sub;
  bool rvalid = (n_row < N_NODES);

  // lane's byte offset inside each (jt,ks) 1KB block
  const int mq16 = (m_n * 4 + quad) * 16;
  const char* BsB = (const char*)Bs;

  // prefetch all 4 chunks' s-vectors (i = ch*16 + quad*4 + r)
  float4 sv[4];
#pragma unroll
  for (int ch = 0; ch < 4; ch++) {
    sv[ch] = rvalid
      ? *reinterpret_cast<const float4*>(s + (size_t)n_row * HID + ch * 16 + quad * 4)
      : make_float4(0.f, 0.f, 0.f, 0.f);
  }

  // prologue: stage ch0 (8 x uint4 per thread, contiguous per wave)
  const uint4* Bg = (const uint4*)Brep;     // 2048 uint4 per ch-slice
  uint4* Bs4 = (uint4*)Bs;
  uint4 st[8];
#pragma unroll
  for (int it = 0; it < 8; it++) st[it] = Bg[it * 256 + t];
#pragma unroll
  for (int it = 0; it < 8; it++) Bs4[it * 256 + t] = st[it];
  __syncthreads();

  floatx4 acc[4];
#pragma unroll
  for (int jt = 0; jt < 4; jt++) acc[jt] = (floatx4){0.f, 0.f, 0.f, 0.f};

#pragma unroll
  for (int ch = 0; ch < 4; ch++) {
    // issue next ch-slice loads first: latency hides under build + MFMA
    if (ch < 3) {
#pragma unroll
      for (int it = 0; it < 8; it++) st[it] = Bg[(ch + 1) * 2048 + it * 256 + t];
    }

    // ---- build A fragments (lane-local, registers only) ----
    short8 afr[8];
    float ss[4] = {sv[ch].x, sv[ch].y, sv[ch].z, sv[ch].w};
#pragma unroll
    for (int r = 0; r < 4; r++) {
      float s1, c1;
      __sincosf(ss[r], &s1, &c1);
      float ck = c1, sk = s1;
      unsigned wbuf[8];
#pragma unroll
      for (int km1 = 0; km1 < 8; km1++) {
        wbuf[km1] = cvtpk_bf16x2(ck, sk);
        float cn = fmaf(ck, c1, -sk * s1);
        float sn = fmaf(sk, c1, ck * s1);
        ck = cn; sk = sn;
      }
      uintx4 lo = (uintx4){wbuf[0], wbuf[1], wbuf[2], wbuf[3]};
      uintx4 hi = (uintx4){wbuf[4], wbuf[5], wbuf[6], wbuf[7]};
      memcpy(&afr[2 * r], &lo, 16);
      memcpy(&afr[2 * r + 1], &hi, 16);
    }

    // ---- MFMA from LDS: (jt,ks) read = contiguous 1KB block ----
#pragma unroll
    for (int ks = 0; ks < 8; ks++) {
      short8 af = afr[ks];
#pragma unroll
      for (int jt = 0; jt < 4; jt++) {
        short8 bf = *reinterpret_cast<const short8*>(BsB + (jt * 8 + ks) * 1024 + mq16);
        acc[jt] = __builtin_amdgcn_mfma_f32_16x16x32_bf16(af, bf, acc[jt], 0, 0, 0);
      }
    }

    __syncthreads();               // all reads of Bs complete
    if (ch < 3) {
#pragma unroll
      for (int it = 0; it < 8; it++) Bs4[it * 256 + t] = st[it];
      __syncthreads();             // next slice visible
    }
  }

  // ---- epilogue: D col=lane&15 (j), row=quad*4+reg (node) ----
#pragma unroll
  for (int jt = 0; jt < 4; jt++) {
#pragma unroll
    for (int reg = 0; reg < 4; reg++) {
      int node = nb * 64 + wv * 16 + quad * 4 + reg;
      if (node < N_NODES)
        out[(size_t)node * HID + jt * 16 + m_n] = acc[jt][reg];
    }
  }
}

// ---------------------------------------------------------------- final linear + log_softmax
__global__ __launch_bounds__(256) void final_kernel(
    const float* __restrict__ h, const float* __restrict__ Wout,
    float* __restrict__ out) {
  __shared__ float Ws[HID * OUT_FEAT];
  __shared__ float hs[4][HID];
  int t = threadIdx.x;
  for (int idx = t; idx < HID * OUT_FEAT; idx += 256)
    Ws[idx] = Wout[idx];
  int wave = t >> 6, lane = t & 63;
  int n = blockIdx.x * 4 + wave;
  hs[wave][lane] = h[(size_t)n * HID + lane];
  __syncthreads();
  float d = 0.f;
  if (lane < OUT_FEAT) {
#pragma unroll 8
    for (int i = 0; i < HID; i++)
      d = fmaf(hs[wave][i], Ws[i * OUT_FEAT + lane], d);
  }
  float m = (lane < OUT_FEAT) ? d : -1e30f;
#pragma unroll
  for (int off = 32; off; off >>= 1) m = fmaxf(m, __shfl_xor(m, off));
  float ex = (lane < OUT_FEAT) ? expf(d - m) : 0.f;
  float ssum = ex;
#pragma unroll
  for (int off = 32; off; off >>= 1) ssum += __shfl_xor(ssum, off);
  float lse = m + logf(ssum);
  if (lane < OUT_FEAT)
    out[(size_t)n * OUT_FEAT + lane] = d - lse;
}

// ---------------------------------------------------------------- launch
extern "C" void kernel_launch(void* const* d_in, const int* in_sizes, int n_in,
                              void* d_out, int out_size, void* d_ws, size_t ws_size,
                              hipStream_t stream) {
  (void)in_sizes; (void)n_in; (void)out_size; (void)ws_size;
  const float* x    = (const float*)d_in[0];
  const int*   erow = (const int*)d_in[1];
  const int*   ecol = (const int*)d_in[2];
  const float* ew   = (const float*)d_in[3];
  const float* W_in = (const float*)d_in[4];
  const float* b_in = (const float*)d_in[5];
  const float* c1   = (const float*)d_in[6];
  const float* c2   = (const float*)d_in[7];
  const float* Wout = (const float*)d_in[8];
  float* out = (float*)d_out;

  float* h   = (float*)d_ws;
  float* acc = h + NELEM;

  // x buffer (12.8M words, 51.2MB) is consumed by lin_in, then reused:
  unsigned* xw     = (unsigned*)(void*)x;
  unsigned* Brep1  = xw;                     // [0, 32768)
  unsigned* Brep2  = xw + 32768;             // [32768, 65536)
  int*      btail  = (int*)(xw + 65536);     // 98
  int*      rowptr = (int*)(xw + 66048);     // 100001
  uint2*    pack1  = (uint2*)(xw + 262144);  // 98*18432 uint2 (ends 3,874,816)
  uint2*    pack2  = (uint2*)(xw + 3932160); // 1.6M uint2 (ends 7,132,160)

  lin_in_kernel<<<N_NODES / 16, 256, 0, stream>>>(x, W_in, b_in, h);

  repack_kernel<<<128, 256, 0, stream>>>(c1, Brep1);
  repack_kernel<<<128, 256, 0, stream>>>(c2, Brep2);

  binit_kernel<<<1, 128, 0, stream>>>(btail);
  bin_kernel<<<BIN_BLOCKS, 256, 0, stream>>>(erow, ecol, ew, btail, pack1);
  bucket_finalize_kernel<<<NB, 256, 0, stream>>>(btail, pack1, rowptr, pack2);

  spmm_csr_kernel<<<N_NODES / 4, 256, 0, stream>>>(rowptr, pack2, h, acc);
  kan_mfma_kernel<<<(N_NODES + 63) / 64, 256, 0, stream>>>(acc, Brep1, h);

  spmm_csr_kernel<<<N_NODES / 4, 256, 0, stream>>>(rowptr, pack2, h, acc);
  kan_mfma_kernel<<<(N_NODES + 63) / 64, 256, 0, stream>>>(acc, Brep2, h);

  final_kernel<<<N_NODES / 4, 256, 0, stream>>>(h, Wout, out);
}

// Round 6
// 463.573 us; speedup vs baseline: 1.3275x; 1.1698x over previous
//
#include <hip/hip_runtime.h>
#include <hip/hip_bf16.h>
#include <string.h>

// KanGNN. Inputs f32 + int32, output f32.
// R16: kan_mfma staging via __builtin_amdgcn_global_load_lds (width 16).
// R15's reg-staged prefetch was spilled to scratch by the compiler
// (VGPR=52, WRITE_SIZE 175MB vs 25.6MB of real output => ~150MB scratch
// round-trip), and the ds_read offset (m_n*4+quad)*16 gave 8-way bank
// conflicts (SQ_LDS_BANK_CONFLICT=3.2M). Fix:
//  - double-buffered 2x16KB half-slices, async global->LDS (no VGPRs, no
//    spill), half h+1 issued right after h's barrier -> latency hides under
//    build+MFMA; vmcnt drains at the next barrier exactly when needed.
//  - repack re-linearized so each (jt,ks) 1KB block is read at lane*16
//    (contiguous ds_read_b128, conflict-free). Fragment VALUES unchanged.
// R13/R14: lane-local A build (K-axis permutation applied to A+B equally).
// R11: 2-level binned counting-sort CSR build (unchanged).

#define N_NODES 100000
#define IN_FEAT 128
#define HID 64
#define OUT_FEAT 40
#define NGRID 8
#define N_EDGES 1600000
#define NELEM (N_NODES * HID)

#define NB 98            // buckets: row >> 10
#define CAP 18432        // per-bucket capacity (mean 16384, sigma ~127)
#define BCHUNK 4096      // edges per bin block
#define BIN_BLOCKS ((N_EDGES + BCHUNK - 1) / BCHUNK)   // 391

using short8 = __attribute__((ext_vector_type(8))) short;
using floatx4 = __attribute__((ext_vector_type(4))) float;
using uintx4 = __attribute__((ext_vector_type(4))) unsigned;

// async 16B/lane global->LDS; lds dest = wave-uniform base + lane*16
#define GLOAD_LDS16(gp, lp)                                                   \
  __builtin_amdgcn_global_load_lds(                                           \
      (const __attribute__((address_space(1))) unsigned*)(gp),                \
      (__attribute__((address_space(3))) unsigned*)(lp), 16, 0, 0)

// f32 -> bf16 RNE, packed pair (lo = c, hi = s) — bit-manip form (repack
// path; keeps B coefficient rounding byte-identical to R11..R15)
__device__ __forceinline__ unsigned pack_bf16x2(float c, float s) {
  unsigned uc = __float_as_uint(c);
  unsigned us = __float_as_uint(s);
  uc += 0x7fffu + ((uc >> 16) & 1u);
  us += 0x7fffu + ((us >> 16) & 1u);
  return (uc >> 16) | (us & 0xffff0000u);
}

// same RNE conversion via v_cvt_pk_bf16_f32 (1 instr instead of ~11)
__device__ __forceinline__ unsigned cvtpk_bf16x2(float c, float s) {
  __hip_bfloat162 p = __float22bfloat162_rn(make_float2(c, s));
  unsigned r;
  memcpy(&r, &p, 4);
  return r;
}

// ---------------------------------------------------------------- lin_in
__global__ __launch_bounds__(256) void lin_in_kernel(
    const float* __restrict__ x, const float* __restrict__ W,
    const float* __restrict__ b, float* __restrict__ h) {
  __shared__ __align__(16) float xs[16 * IN_FEAT];   // 8 KB
  int t = threadIdx.x;
  int nb = blockIdx.x;
  const float4* xsrc = (const float4*)(x + (size_t)nb * 16 * IN_FEAT);
  float4* xd = (float4*)xs;
  xd[t] = xsrc[t];
  xd[t + 256] = xsrc[t + 256];
  __syncthreads();
  int lane = t & 63, wv = t >> 6;
  float bj = b[lane];
  float a0 = bj, a1 = bj, a2 = bj, a3 = bj;
  const float* xr = xs + wv * 4 * IN_FEAT;
  const float* Wj = W + lane;
#pragma unroll 4
  for (int i4 = 0; i4 < 32; i4++) {
    float4 x0 = *(const float4*)(xr + 0 * IN_FEAT + i4 * 4);
    float4 x1 = *(const float4*)(xr + 1 * IN_FEAT + i4 * 4);
    float4 x2 = *(const float4*)(xr + 2 * IN_FEAT + i4 * 4);
    float4 x3 = *(const float4*)(xr + 3 * IN_FEAT + i4 * 4);
    float w0 = Wj[(i4 * 4 + 0) * HID];
    float w1 = Wj[(i4 * 4 + 1) * HID];
    float w2 = Wj[(i4 * 4 + 2) * HID];
    float w3 = Wj[(i4 * 4 + 3) * HID];
    a0 = fmaf(x0.x, w0, a0); a0 = fmaf(x0.y, w1, a0); a0 = fmaf(x0.z, w2, a0); a0 = fmaf(x0.w, w3, a0);
    a1 = fmaf(x1.x, w0, a1); a1 = fmaf(x1.y, w1, a1); a1 = fmaf(x1.z, w2, a1); a1 = fmaf(x1.w, w3, a1);
    a2 = fmaf(x2.x, w0, a2); a2 = fmaf(x2.y, w1, a2); a2 = fmaf(x2.z, w2, a2); a2 = fmaf(x2.w, w3, a2);
    a3 = fmaf(x3.x, w0, a3); a3 = fmaf(x3.y, w1, a3); a3 = fmaf(x3.z, w2, a3); a3 = fmaf(x3.w, w3, a3);
  }
  size_t nbase = (size_t)nb * 16 + wv * 4;
  h[(nbase + 0) * HID + lane] = a0;
  h[(nbase + 1) * HID + lane] = a1;
  h[(nbase + 2) * HID + lane] = a2;
  h[(nbase + 3) * HID + lane] = a3;
}

// ---------------------------------------------------------------- CSR build (R11)
__global__ __launch_bounds__(128) void binit_kernel(int* __restrict__ btail) {
  int t = threadIdx.x;
  if (t < NB) btail[t] = t * CAP;
}

// Pass 1: coarse-bucket counting sort.
__global__ __launch_bounds__(256) void bin_kernel(
    const int* __restrict__ row, const int* __restrict__ col,
    const float* __restrict__ w, int* __restrict__ btail,
    uint2* __restrict__ pack1) {
  __shared__ __align__(16) uint2 stage[BCHUNK];   // 32 KB
  __shared__ int bcnt[NB];
  __shared__ int lbase[NB];
  __shared__ int gbase[NB];
  __shared__ int lcur[NB];
  __shared__ int sc[128];
  int t = threadIdx.x;
  int e0 = blockIdx.x * BCHUNK;
  if (t < NB) bcnt[t] = 0;
  __syncthreads();
  int rloc[16];
#pragma unroll
  for (int q = 0; q < 16; q++) {
    int e = e0 + q * 256 + t;
    int r = (e < N_EDGES) ? row[e] : -1;
    rloc[q] = r;
    if (r >= 0) atomicAdd(&bcnt[r >> 10], 1);
  }
  __syncthreads();
  int c = (t < NB) ? bcnt[t] : 0;
  if (t < 128) sc[t] = c;
  __syncthreads();
  int v = c;
#pragma unroll
  for (int off = 1; off < 128; off <<= 1) {
    int add = (t >= off && t < 128) ? sc[t - off] : 0;
    __syncthreads();
    if (t < 128) sc[t] = v = v + add;
    __syncthreads();
  }
  if (t < NB) {
    lbase[t] = v - c;
    lcur[t] = v - c;
    gbase[t] = atomicAdd(&btail[t], c);
  }
  __syncthreads();
#pragma unroll
  for (int q = 0; q < 16; q++) {
    int e = e0 + q * 256 + t;
    int r = rloc[q];
    if (r >= 0) {
      int p = atomicAdd(&lcur[r >> 10], 1);
      unsigned key = ((unsigned)(r & 1023) << 17) | (unsigned)col[e];
      stage[p] = make_uint2(key, __float_as_uint(w[e]));
    }
  }
  __syncthreads();
  int wv = t >> 6, lane = t & 63;
  for (int b = wv; b < NB; b += 4) {
    int len = bcnt[b], src = lbase[b];
    uint2* dst = pack1 + (size_t)gbase[b];
    for (int i = lane; i < len; i += 64)
      dst[i] = stage[src + i];
  }
}

// Pass 2: one block per bucket -> rowptr + exact scatter.
__global__ __launch_bounds__(256) void bucket_finalize_kernel(
    const int* __restrict__ btail, const uint2* __restrict__ pack1,
    int* __restrict__ rowptr, uint2* __restrict__ pack2) {
  __shared__ int rcnt[1024];
  __shared__ int sc[256];
  __shared__ int binfo[2];
  int b = blockIdx.x, t = threadIdx.x;
  if (t < NB) sc[t] = btail[t] - t * CAP;   // per-bucket counts
  rcnt[t] = 0; rcnt[t + 256] = 0; rcnt[t + 512] = 0; rcnt[t + 768] = 0;
  __syncthreads();
  if (t == 0) {
    int base = 0;
    for (int i = 0; i < b; i++) base += sc[i];
    binfo[0] = base;
    binfo[1] = sc[b];
  }
  __syncthreads();
  int base = binfo[0], len = binfo[1];
  const uint2* rec = pack1 + (size_t)b * CAP;
  for (int i = t; i < len; i += 256)
    atomicAdd(&rcnt[rec[i].x >> 17], 1);
  __syncthreads();
  int c0 = rcnt[4 * t], c1 = rcnt[4 * t + 1], c2 = rcnt[4 * t + 2], c3 = rcnt[4 * t + 3];
  int s4 = c0 + c1 + c2 + c3;
  sc[t] = s4;
  __syncthreads();
  int v = s4;
#pragma unroll
  for (int off = 1; off < 256; off <<= 1) {
    int add = (t >= off) ? sc[t - off] : 0;
    __syncthreads();
    sc[t] = v = v + add;
    __syncthreads();
  }
  int excl = v - s4;
  int p0 = base + excl;
  int p1 = p0 + c0, p2 = p1 + c1, p3 = p2 + c2;
  int r0 = (b << 10) + 4 * t;
  if (r0 + 0 < N_NODES) rowptr[r0 + 0] = p0;
  if (r0 + 1 < N_NODES) rowptr[r0 + 1] = p1;
  if (r0 + 2 < N_NODES) rowptr[r0 + 2] = p2;
  if (r0 + 3 < N_NODES) rowptr[r0 + 3] = p3;
  rcnt[4 * t] = p0; rcnt[4 * t + 1] = p1; rcnt[4 * t + 2] = p2; rcnt[4 * t + 3] = p3;
  __syncthreads();
  for (int i = t; i < len; i += 256) {
    uint2 p = rec[i];
    int pos = atomicAdd(&rcnt[p.x >> 17], 1);
    pack2[pos] = make_uint2(p.x & 0x1FFFFu, p.y);
  }
  if (b == NB - 1 && t == 0) rowptr[N_NODES] = N_EDGES;
}

// ---------------------------------------------------------------- spmm (CSR, atomic-free)
__global__ __launch_bounds__(256) void spmm_csr_kernel(
    const int* __restrict__ rowptr, const uint2* __restrict__ pack,
    const float* __restrict__ h, float* __restrict__ acc) {
  int wv = threadIdx.x >> 6, lane = threadIdx.x & 63;
  int n = blockIdx.x * 4 + wv;
  int beg = rowptr[n], end = rowptr[n + 1];
  int slot = lane >> 4, f4 = lane & 15;
  const float4* h4 = (const float4*)h;
  float4 v = make_float4(0.f, 0.f, 0.f, 0.f);
  for (int e = beg; e < end; e += 4) {
    int idx = e + slot;
    int col = 0;
    float wt = 0.f;
    if (idx < end) {
      uint2 p = pack[idx];
      col = (int)p.x;
      wt = __uint_as_float(p.y);
    }
    float4 hv = h4[(size_t)col * 16 + f4];
    v.x = fmaf(wt, hv.x, v.x);
    v.y = fmaf(wt, hv.y, v.y);
    v.z = fmaf(wt, hv.z, v.z);
    v.w = fmaf(wt, hv.w, v.w);
  }
#pragma unroll
  for (int off = 16; off < 64; off <<= 1) {
    v.x += __shfl_xor(v.x, off);
    v.y += __shfl_xor(v.y, off);
    v.z += __shfl_xor(v.z, off);
    v.w += __shfl_xor(v.w, off);
  }
  if (slot == 0)
    ((float4*)acc)[(size_t)n * 16 + f4] = v;
}

// ---------------------------------------------------------------- repack
// R16 layout: word idx = ch*8192 + (jt*8+ks)*256 + (quad*16 + m_n)*4 + jj.
// -> each (jt,ks) 1KB block is read by lane=(quad<<4)|m_n at byte lane*16
// (contiguous, conflict-free ds_read_b128); staging is a straight copy.
// Fragment content identical to R14/R15:
//   r = ks>>1, km1 = ((ks&1)<<2)|jj, i = ch*16 + 4*quad + r, j = jt*16+m_n.
__global__ __launch_bounds__(256) void repack_kernel(
    const float* __restrict__ coeffs, unsigned* __restrict__ Brep) {
  int idx = blockIdx.x * 256 + threadIdx.x;   // 32768 words
  int ch = idx >> 13;
  int rem = idx & 8191;
  int blk = rem >> 8;           // jt*8+ks, 0..31
  int jt = blk >> 3, ks = blk & 7;
  int rem2 = rem & 255;
  int ls = rem2 >> 2;           // lane slot = quad*16 + m_n
  int quad = ls >> 4, m_n = ls & 15;
  int jj = rem2 & 3;
  int j = jt * 16 + m_n;
  int r = ks >> 1, km1 = ((ks & 1) << 2) | jj;
  int i = ch * 16 + quad * 4 + r;
  int ws = i * 8 + km1;
  float c0 = coeffs[(size_t)j * 512 + ws];
  float c1 = coeffs[32768 + (size_t)j * 512 + ws];
  Brep[idx] = pack_bf16x2(c0, c1);
}

// ---------------------------------------------------------------- KAN via MFMA
// (B via async global_load_lds, double-buffered 16KB half-slices)
// 8 halves: h -> ch = h>>1, jt-pair = h&1 (jt = 2*(h&1), 2*(h&1)+1).
// Per h: barrier (drains h's loads) -> issue h+1's loads into the other
// buffer -> (even h) build A fragments -> 16 MFMA from LDS. One-deep
// pipeline; staging uses zero VGPRs (no spill possible).
__global__ __launch_bounds__(256, 4) void kan_mfma_kernel(
    const float* __restrict__ s, const unsigned* __restrict__ Brep,
    float* __restrict__ out) {
  __shared__ __align__(16) unsigned Bs[2][4096];   // 2 x 16 KB
  int t = threadIdx.x;
  int lane = t & 63;
  int wv = t >> 6;
  int nb = blockIdx.x;

  int m_n = lane & 15;            // A row within 16x16 tile
  int quad = lane >> 4;           // k-quad of the MFMA fragment
  int node_sub = wv * 16 + m_n;
  int n_row = nb * 64 + node_sub;
  bool rvalid = (n_row < N_NODES);

  const char* Gb = (const char*)Brep;   // 8 halves x 16KB, linear

  // issue half 0 (4 x 1KB chunks per wave; chunk c = i*4 + wv)
#pragma unroll
  for (int i = 0; i < 4; i++) {
    int c = i * 4 + wv;
    GLOAD_LDS16(Gb + c * 1024 + lane * 16, (char*)&Bs[0][0] + c * 1024);
  }

  // prefetch all 4 chunks' s-vectors (i = ch*16 + quad*4 + r)
  float4 sv[4];
#pragma unroll
  for (int ch = 0; ch < 4; ch++) {
    sv[ch] = rvalid
      ? *reinterpret_cast<const float4*>(s + (size_t)n_row * HID + ch * 16 + quad * 4)
      : make_float4(0.f, 0.f, 0.f, 0.f);
  }

  floatx4 acc[4];
#pragma unroll
  for (int jt = 0; jt < 4; jt++) acc[jt] = (floatx4){0.f, 0.f, 0.f, 0.f};

  short8 afr[8];

#pragma unroll
  for (int h = 0; h < 8; h++) {
    // drain this half's loads (and prior LDS reads), sync all waves
    asm volatile("s_waitcnt vmcnt(0)" ::: "memory");
    __syncthreads();

    // issue next half into the other buffer (safe: its last readers
    // finished before the barrier above); latency hides under build+MFMA
    if (h < 7) {
      const char* gsrc = Gb + (h + 1) * 16384;
      char* ldst = (char*)&Bs[(h + 1) & 1][0];
#pragma unroll
      for (int i = 0; i < 4; i++) {
        int c = i * 4 + wv;
        GLOAD_LDS16(gsrc + c * 1024 + lane * 16, ldst + c * 1024);
      }
    }

    // build A fragments at the start of each ch (even h); reused by odd h
    if ((h & 1) == 0) {
      int ch = h >> 1;
      float ss[4] = {sv[ch].x, sv[ch].y, sv[ch].z, sv[ch].w};
#pragma unroll
      for (int r = 0; r < 4; r++) {
        float s1, c1;
        __sincosf(ss[r], &s1, &c1);
        float ck = c1, sk = s1;
        unsigned wbuf[8];
#pragma unroll
        for (int km1 = 0; km1 < 8; km1++) {
          wbuf[km1] = cvtpk_bf16x2(ck, sk);
          float cn = fmaf(ck, c1, -sk * s1);
          float sn = fmaf(sk, c1, ck * s1);
          ck = cn; sk = sn;
        }
        uintx4 lo = (uintx4){wbuf[0], wbuf[1], wbuf[2], wbuf[3]};
        uintx4 hi = (uintx4){wbuf[4], wbuf[5], wbuf[6], wbuf[7]};
        memcpy(&afr[2 * r], &lo, 16);
        memcpy(&afr[2 * r + 1], &hi, 16);
      }
    }

    // ---- MFMA from LDS: lane reads at lane*16 within each 1KB block ----
    const char* Bb = (const char*)&Bs[h & 1][0];
    int jtp = (h & 1) * 2;
#pragma unroll
    for (int ks = 0; ks < 8; ks++) {
      short8 af = afr[ks];
#pragma unroll
      for (int j2 = 0; j2 < 2; j2++) {
        short8 bf = *reinterpret_cast<const short8*>(Bb + (j2 * 8 + ks) * 1024 + lane * 16);
        acc[jtp + j2] = __builtin_amdgcn_mfma_f32_16x16x32_bf16(af, bf, acc[jtp + j2], 0, 0, 0);
      }
    }
  }

  // ---- epilogue: D col=lane&15 (j), row=quad*4+reg (node) ----
#pragma unroll
  for (int jt = 0; jt < 4; jt++) {
#pragma unroll
    for (int reg = 0; reg < 4; reg++) {
      int node = nb * 64 + wv * 16 + quad * 4 + reg;
      if (node < N_NODES)
        out[(size_t)node * HID + jt * 16 + m_n] = acc[jt][reg];
    }
  }
}

// ---------------------------------------------------------------- final linear + log_softmax
__global__ __launch_bounds__(256) void final_kernel(
    const float* __restrict__ h, const float* __restrict__ Wout,
    float* __restrict__ out) {
  __shared__ float Ws[HID * OUT_FEAT];
  __shared__ float hs[4][HID];
  int t = threadIdx.x;
  for (int idx = t; idx < HID * OUT_FEAT; idx += 256)
    Ws[idx] = Wout[idx];
  int wave = t >> 6, lane = t & 63;
  int n = blockIdx.x * 4 + wave;
  hs[wave][lane] = h[(size_t)n * HID + lane];
  __syncthreads();
  float d = 0.f;
  if (lane < OUT_FEAT) {
#pragma unroll 8
    for (int i = 0; i < HID; i++)
      d = fmaf(hs[wave][i], Ws[i * OUT_FEAT + lane], d);
  }
  float m = (lane < OUT_FEAT) ? d : -1e30f;
#pragma unroll
  for (int off = 32; off; off >>= 1) m = fmaxf(m, __shfl_xor(m, off));
  float ex = (lane < OUT_FEAT) ? expf(d - m) : 0.f;
  float ssum = ex;
#pragma unroll
  for (int off = 32; off; off >>= 1) ssum += __shfl_xor(ssum, off);
  float lse = m + logf(ssum);
  if (lane < OUT_FEAT)
    out[(size_t)n * OUT_FEAT + lane] = d - lse;
}

// ---------------------------------------------------------------- launch
extern "C" void kernel_launch(void* const* d_in, const int* in_sizes, int n_in,
                              void* d_out, int out_size, void* d_ws, size_t ws_size,
                              hipStream_t stream) {
  (void)in_sizes; (void)n_in; (void)out_size; (void)ws_size;
  const float* x    = (const float*)d_in[0];
  const int*   erow = (const int*)d_in[1];
  const int*   ecol = (const int*)d_in[2];
  const float* ew   = (const float*)d_in[3];
  const float* W_in = (const float*)d_in[4];
  const float* b_in = (const float*)d_in[5];
  const float* c1   = (const float*)d_in[6];
  const float* c2   = (const float*)d_in[7];
  const float* Wout = (const float*)d_in[8];
  float* out = (float*)d_out;

  float* h   = (float*)d_ws;
  float* acc = h + NELEM;

  // x buffer (12.8M words, 51.2MB) is consumed by lin_in, then reused:
  unsigned* xw     = (unsigned*)(void*)x;
  unsigned* Brep1  = xw;                     // [0, 32768)
  unsigned* Brep2  = xw + 32768;             // [32768, 65536)
  int*      btail  = (int*)(xw + 65536);     // 98
  int*      rowptr = (int*)(xw + 66048);     // 100001
  uint2*    pack1  = (uint2*)(xw + 262144);  // 98*18432 uint2 (ends 3,874,816)
  uint2*    pack2  = (uint2*)(xw + 3932160); // 1.6M uint2 (ends 7,132,160)

  lin_in_kernel<<<N_NODES / 16, 256, 0, stream>>>(x, W_in, b_in, h);

  repack_kernel<<<128, 256, 0, stream>>>(c1, Brep1);
  repack_kernel<<<128, 256, 0, stream>>>(c2, Brep2);

  binit_kernel<<<1, 128, 0, stream>>>(btail);
  bin_kernel<<<BIN_BLOCKS, 256, 0, stream>>>(erow, ecol, ew, btail, pack1);
  bucket_finalize_kernel<<<NB, 256, 0, stream>>>(btail, pack1, rowptr, pack2);

  spmm_csr_kernel<<<N_NODES / 4, 256, 0, stream>>>(rowptr, pack2, h, acc);
  kan_mfma_kernel<<<(N_NODES + 63) / 64, 256, 0, stream>>>(acc, Brep1, h);

  spmm_csr_kernel<<<N_NODES / 4, 256, 0, stream>>>(rowptr, pack2, h, acc);
  kan_mfma_kernel<<<(N_NODES + 63) / 64, 256, 0, stream>>>(acc, Brep2, h);

  final_kernel<<<N_NODES / 4, 256, 0, stream>>>(h, Wout, out);
}

// Round 7
// 440.121 us; speedup vs baseline: 1.3982x; 1.0533x over previous
//
#include <hip/hip_runtime.h>
#include <hip/hip_bf16.h>
#include <string.h>

// KanGNN. Inputs f32 + int32, output f32.
// R17: final_kernel rewrite. Old: one node per WAVE, inner loop =
// 2 scalar ds_read_b32 per fmaf (128 LDS instrs/node), 64-deep serial fmaf
// chain, 40/64 lanes -> LDS-issue-bound at 68.5us (10x roofline).
// New: W column in registers (lane j holds Wout[:,j], 64 VGPR), h staged
// 64 nodes/block (16KB), wave processes 16 nodes 2-at-a-time: 16 broadcast
// ds_read_b128 + 64 fmaf per node, two independent chains for ILP.
// Same accumulation order (i ascending, d starts 0) -> bit-identical output.
// R16: kan_mfma async global_load_lds dbuf staging + conflict-free layout.
// R13/R14: lane-local A build. R11: binned counting-sort CSR build.

#define N_NODES 100000
#define IN_FEAT 128
#define HID 64
#define OUT_FEAT 40
#define NGRID 8
#define N_EDGES 1600000
#define NELEM (N_NODES * HID)

#define NB 98            // buckets: row >> 10
#define CAP 18432        // per-bucket capacity (mean 16384, sigma ~127)
#define BCHUNK 4096      // edges per bin block
#define BIN_BLOCKS ((N_EDGES + BCHUNK - 1) / BCHUNK)   // 391

using short8 = __attribute__((ext_vector_type(8))) short;
using floatx4 = __attribute__((ext_vector_type(4))) float;
using uintx4 = __attribute__((ext_vector_type(4))) unsigned;

// async 16B/lane global->LDS; lds dest = wave-uniform base + lane*16
#define GLOAD_LDS16(gp, lp)                                                   \
  __builtin_amdgcn_global_load_lds(                                           \
      (const __attribute__((address_space(1))) unsigned*)(gp),                \
      (__attribute__((address_space(3))) unsigned*)(lp), 16, 0, 0)

// f32 -> bf16 RNE, packed pair (lo = c, hi = s) — bit-manip form (repack
// path; keeps B coefficient rounding byte-identical to R11..R16)
__device__ __forceinline__ unsigned pack_bf16x2(float c, float s) {
  unsigned uc = __float_as_uint(c);
  unsigned us = __float_as_uint(s);
  uc += 0x7fffu + ((uc >> 16) & 1u);
  us += 0x7fffu + ((us >> 16) & 1u);
  return (uc >> 16) | (us & 0xffff0000u);
}

// same RNE conversion via v_cvt_pk_bf16_f32 (1 instr instead of ~11)
__device__ __forceinline__ unsigned cvtpk_bf16x2(float c, float s) {
  __hip_bfloat162 p = __float22bfloat162_rn(make_float2(c, s));
  unsigned r;
  memcpy(&r, &p, 4);
  return r;
}

// ---------------------------------------------------------------- lin_in
__global__ __launch_bounds__(256) void lin_in_kernel(
    const float* __restrict__ x, const float* __restrict__ W,
    const float* __restrict__ b, float* __restrict__ h) {
  __shared__ __align__(16) float xs[16 * IN_FEAT];   // 8 KB
  int t = threadIdx.x;
  int nb = blockIdx.x;
  const float4* xsrc = (const float4*)(x + (size_t)nb * 16 * IN_FEAT);
  float4* xd = (float4*)xs;
  xd[t] = xsrc[t];
  xd[t + 256] = xsrc[t + 256];
  __syncthreads();
  int lane = t & 63, wv = t >> 6;
  float bj = b[lane];
  float a0 = bj, a1 = bj, a2 = bj, a3 = bj;
  const float* xr = xs + wv * 4 * IN_FEAT;
  const float* Wj = W + lane;
#pragma unroll 4
  for (int i4 = 0; i4 < 32; i4++) {
    float4 x0 = *(const float4*)(xr + 0 * IN_FEAT + i4 * 4);
    float4 x1 = *(const float4*)(xr + 1 * IN_FEAT + i4 * 4);
    float4 x2 = *(const float4*)(xr + 2 * IN_FEAT + i4 * 4);
    float4 x3 = *(const float4*)(xr + 3 * IN_FEAT + i4 * 4);
    float w0 = Wj[(i4 * 4 + 0) * HID];
    float w1 = Wj[(i4 * 4 + 1) * HID];
    float w2 = Wj[(i4 * 4 + 2) * HID];
    float w3 = Wj[(i4 * 4 + 3) * HID];
    a0 = fmaf(x0.x, w0, a0); a0 = fmaf(x0.y, w1, a0); a0 = fmaf(x0.z, w2, a0); a0 = fmaf(x0.w, w3, a0);
    a1 = fmaf(x1.x, w0, a1); a1 = fmaf(x1.y, w1, a1); a1 = fmaf(x1.z, w2, a1); a1 = fmaf(x1.w, w3, a1);
    a2 = fmaf(x2.x, w0, a2); a2 = fmaf(x2.y, w1, a2); a2 = fmaf(x2.z, w2, a2); a2 = fmaf(x2.w, w3, a2);
    a3 = fmaf(x3.x, w0, a3); a3 = fmaf(x3.y, w1, a3); a3 = fmaf(x3.z, w2, a3); a3 = fmaf(x3.w, w3, a3);
  }
  size_t nbase = (size_t)nb * 16 + wv * 4;
  h[(nbase + 0) * HID + lane] = a0;
  h[(nbase + 1) * HID + lane] = a1;
  h[(nbase + 2) * HID + lane] = a2;
  h[(nbase + 3) * HID + lane] = a3;
}

// ---------------------------------------------------------------- CSR build (R11)
__global__ __launch_bounds__(128) void binit_kernel(int* __restrict__ btail) {
  int t = threadIdx.x;
  if (t < NB) btail[t] = t * CAP;
}

// Pass 1: coarse-bucket counting sort.
__global__ __launch_bounds__(256) void bin_kernel(
    const int* __restrict__ row, const int* __restrict__ col,
    const float* __restrict__ w, int* __restrict__ btail,
    uint2* __restrict__ pack1) {
  __shared__ __align__(16) uint2 stage[BCHUNK];   // 32 KB
  __shared__ int bcnt[NB];
  __shared__ int lbase[NB];
  __shared__ int gbase[NB];
  __shared__ int lcur[NB];
  __shared__ int sc[128];
  int t = threadIdx.x;
  int e0 = blockIdx.x * BCHUNK;
  if (t < NB) bcnt[t] = 0;
  __syncthreads();
  int rloc[16];
#pragma unroll
  for (int q = 0; q < 16; q++) {
    int e = e0 + q * 256 + t;
    int r = (e < N_EDGES) ? row[e] : -1;
    rloc[q] = r;
    if (r >= 0) atomicAdd(&bcnt[r >> 10], 1);
  }
  __syncthreads();
  int c = (t < NB) ? bcnt[t] : 0;
  if (t < 128) sc[t] = c;
  __syncthreads();
  int v = c;
#pragma unroll
  for (int off = 1; off < 128; off <<= 1) {
    int add = (t >= off && t < 128) ? sc[t - off] : 0;
    __syncthreads();
    if (t < 128) sc[t] = v = v + add;
    __syncthreads();
  }
  if (t < NB) {
    lbase[t] = v - c;
    lcur[t] = v - c;
    gbase[t] = atomicAdd(&btail[t], c);
  }
  __syncthreads();
#pragma unroll
  for (int q = 0; q < 16; q++) {
    int e = e0 + q * 256 + t;
    int r = rloc[q];
    if (r >= 0) {
      int p = atomicAdd(&lcur[r >> 10], 1);
      unsigned key = ((unsigned)(r & 1023) << 17) | (unsigned)col[e];
      stage[p] = make_uint2(key, __float_as_uint(w[e]));
    }
  }
  __syncthreads();
  int wv = t >> 6, lane = t & 63;
  for (int b = wv; b < NB; b += 4) {
    int len = bcnt[b], src = lbase[b];
    uint2* dst = pack1 + (size_t)gbase[b];
    for (int i = lane; i < len; i += 64)
      dst[i] = stage[src + i];
  }
}

// Pass 2: one block per bucket -> rowptr + exact scatter.
__global__ __launch_bounds__(256) void bucket_finalize_kernel(
    const int* __restrict__ btail, const uint2* __restrict__ pack1,
    int* __restrict__ rowptr, uint2* __restrict__ pack2) {
  __shared__ int rcnt[1024];
  __shared__ int sc[256];
  __shared__ int binfo[2];
  int b = blockIdx.x, t = threadIdx.x;
  if (t < NB) sc[t] = btail[t] - t * CAP;   // per-bucket counts
  rcnt[t] = 0; rcnt[t + 256] = 0; rcnt[t + 512] = 0; rcnt[t + 768] = 0;
  __syncthreads();
  if (t == 0) {
    int base = 0;
    for (int i = 0; i < b; i++) base += sc[i];
    binfo[0] = base;
    binfo[1] = sc[b];
  }
  __syncthreads();
  int base = binfo[0], len = binfo[1];
  const uint2* rec = pack1 + (size_t)b * CAP;
  for (int i = t; i < len; i += 256)
    atomicAdd(&rcnt[rec[i].x >> 17], 1);
  __syncthreads();
  int c0 = rcnt[4 * t], c1 = rcnt[4 * t + 1], c2 = rcnt[4 * t + 2], c3 = rcnt[4 * t + 3];
  int s4 = c0 + c1 + c2 + c3;
  sc[t] = s4;
  __syncthreads();
  int v = s4;
#pragma unroll
  for (int off = 1; off < 256; off <<= 1) {
    int add = (t >= off) ? sc[t - off] : 0;
    __syncthreads();
    sc[t] = v = v + add;
    __syncthreads();
  }
  int excl = v - s4;
  int p0 = base + excl;
  int p1 = p0 + c0, p2 = p1 + c1, p3 = p2 + c2;
  int r0 = (b << 10) + 4 * t;
  if (r0 + 0 < N_NODES) rowptr[r0 + 0] = p0;
  if (r0 + 1 < N_NODES) rowptr[r0 + 1] = p1;
  if (r0 + 2 < N_NODES) rowptr[r0 + 2] = p2;
  if (r0 + 3 < N_NODES) rowptr[r0 + 3] = p3;
  rcnt[4 * t] = p0; rcnt[4 * t + 1] = p1; rcnt[4 * t + 2] = p2; rcnt[4 * t + 3] = p3;
  __syncthreads();
  for (int i = t; i < len; i += 256) {
    uint2 p = rec[i];
    int pos = atomicAdd(&rcnt[p.x >> 17], 1);
    pack2[pos] = make_uint2(p.x & 0x1FFFFu, p.y);
  }
  if (b == NB - 1 && t == 0) rowptr[N_NODES] = N_EDGES;
}

// ---------------------------------------------------------------- spmm (CSR, atomic-free)
__global__ __launch_bounds__(256) void spmm_csr_kernel(
    const int* __restrict__ rowptr, const uint2* __restrict__ pack,
    const float* __restrict__ h, float* __restrict__ acc) {
  int wv = threadIdx.x >> 6, lane = threadIdx.x & 63;
  int n = blockIdx.x * 4 + wv;
  int beg = rowptr[n], end = rowptr[n + 1];
  int slot = lane >> 4, f4 = lane & 15;
  const float4* h4 = (const float4*)h;
  float4 v = make_float4(0.f, 0.f, 0.f, 0.f);
  for (int e = beg; e < end; e += 4) {
    int idx = e + slot;
    int col = 0;
    float wt = 0.f;
    if (idx < end) {
      uint2 p = pack[idx];
      col = (int)p.x;
      wt = __uint_as_float(p.y);
    }
    float4 hv = h4[(size_t)col * 16 + f4];
    v.x = fmaf(wt, hv.x, v.x);
    v.y = fmaf(wt, hv.y, v.y);
    v.z = fmaf(wt, hv.z, v.z);
    v.w = fmaf(wt, hv.w, v.w);
  }
#pragma unroll
  for (int off = 16; off < 64; off <<= 1) {
    v.x += __shfl_xor(v.x, off);
    v.y += __shfl_xor(v.y, off);
    v.z += __shfl_xor(v.z, off);
    v.w += __shfl_xor(v.w, off);
  }
  if (slot == 0)
    ((float4*)acc)[(size_t)n * 16 + f4] = v;
}

// ---------------------------------------------------------------- repack
// R16 layout: word idx = ch*8192 + (jt*8+ks)*256 + (quad*16 + m_n)*4 + jj.
// -> each (jt,ks) 1KB block is read by lane=(quad<<4)|m_n at byte lane*16
// (contiguous, conflict-free ds_read_b128); staging is a straight copy.
// Fragment content identical to R14/R15:
//   r = ks>>1, km1 = ((ks&1)<<2)|jj, i = ch*16 + 4*quad + r, j = jt*16+m_n.
__global__ __launch_bounds__(256) void repack_kernel(
    const float* __restrict__ coeffs, unsigned* __restrict__ Brep) {
  int idx = blockIdx.x * 256 + threadIdx.x;   // 32768 words
  int ch = idx >> 13;
  int rem = idx & 8191;
  int blk = rem >> 8;           // jt*8+ks, 0..31
  int jt = blk >> 3, ks = blk & 7;
  int rem2 = rem & 255;
  int ls = rem2 >> 2;           // lane slot = quad*16 + m_n
  int quad = ls >> 4, m_n = ls & 15;
  int jj = rem2 & 3;
  int j = jt * 16 + m_n;
  int r = ks >> 1, km1 = ((ks & 1) << 2) | jj;
  int i = ch * 16 + quad * 4 + r;
  int ws = i * 8 + km1;
  float c0 = coeffs[(size_t)j * 512 + ws];
  float c1 = coeffs[32768 + (size_t)j * 512 + ws];
  Brep[idx] = pack_bf16x2(c0, c1);
}

// ---------------------------------------------------------------- KAN via MFMA
// (B via async global_load_lds, double-buffered 16KB half-slices)
__global__ __launch_bounds__(256, 4) void kan_mfma_kernel(
    const float* __restrict__ s, const unsigned* __restrict__ Brep,
    float* __restrict__ out) {
  __shared__ __align__(16) unsigned Bs[2][4096];   // 2 x 16 KB
  int t = threadIdx.x;
  int lane = t & 63;
  int wv = t >> 6;
  int nb = blockIdx.x;

  int m_n = lane & 15;            // A row within 16x16 tile
  int quad = lane >> 4;           // k-quad of the MFMA fragment
  int node_sub = wv * 16 + m_n;
  int n_row = nb * 64 + node_sub;
  bool rvalid = (n_row < N_NODES);

  const char* Gb = (const char*)Brep;   // 8 halves x 16KB, linear

  // issue half 0 (4 x 1KB chunks per wave; chunk c = i*4 + wv)
#pragma unroll
  for (int i = 0; i < 4; i++) {
    int c = i * 4 + wv;
    GLOAD_LDS16(Gb + c * 1024 + lane * 16, (char*)&Bs[0][0] + c * 1024);
  }

  // prefetch all 4 chunks' s-vectors (i = ch*16 + quad*4 + r)
  float4 sv[4];
#pragma unroll
  for (int ch = 0; ch < 4; ch++) {
    sv[ch] = rvalid
      ? *reinterpret_cast<const float4*>(s + (size_t)n_row * HID + ch * 16 + quad * 4)
      : make_float4(0.f, 0.f, 0.f, 0.f);
  }

  floatx4 acc[4];
#pragma unroll
  for (int jt = 0; jt < 4; jt++) acc[jt] = (floatx4){0.f, 0.f, 0.f, 0.f};

  short8 afr[8];

#pragma unroll
  for (int h = 0; h < 8; h++) {
    // drain this half's loads (and prior LDS reads), sync all waves
    asm volatile("s_waitcnt vmcnt(0)" ::: "memory");
    __syncthreads();

    // issue next half into the other buffer (safe: its last readers
    // finished before the barrier above); latency hides under build+MFMA
    if (h < 7) {
      const char* gsrc = Gb + (h + 1) * 16384;
      char* ldst = (char*)&Bs[(h + 1) & 1][0];
#pragma unroll
      for (int i = 0; i < 4; i++) {
        int c = i * 4 + wv;
        GLOAD_LDS16(gsrc + c * 1024 + lane * 16, ldst + c * 1024);
      }
    }

    // build A fragments at the start of each ch (even h); reused by odd h
    if ((h & 1) == 0) {
      int ch = h >> 1;
      float ss[4] = {sv[ch].x, sv[ch].y, sv[ch].z, sv[ch].w};
#pragma unroll
      for (int r = 0; r < 4; r++) {
        float s1, c1;
        __sincosf(ss[r], &s1, &c1);
        float ck = c1, sk = s1;
        unsigned wbuf[8];
#pragma unroll
        for (int km1 = 0; km1 < 8; km1++) {
          wbuf[km1] = cvtpk_bf16x2(ck, sk);
          float cn = fmaf(ck, c1, -sk * s1);
          float sn = fmaf(sk, c1, ck * s1);
          ck = cn; sk = sn;
        }
        uintx4 lo = (uintx4){wbuf[0], wbuf[1], wbuf[2], wbuf[3]};
        uintx4 hi = (uintx4){wbuf[4], wbuf[5], wbuf[6], wbuf[7]};
        memcpy(&afr[2 * r], &lo, 16);
        memcpy(&afr[2 * r + 1], &hi, 16);
      }
    }

    // ---- MFMA from LDS: lane reads at lane*16 within each 1KB block ----
    const char* Bb = (const char*)&Bs[h & 1][0];
    int jtp = (h & 1) * 2;
#pragma unroll
    for (int ks = 0; ks < 8; ks++) {
      short8 af = afr[ks];
#pragma unroll
      for (int j2 = 0; j2 < 2; j2++) {
        short8 bf = *reinterpret_cast<const short8*>(Bb + (j2 * 8 + ks) * 1024 + lane * 16);
        acc[jtp + j2] = __builtin_amdgcn_mfma_f32_16x16x32_bf16(af, bf, acc[jtp + j2], 0, 0, 0);
      }
    }
  }

  // ---- epilogue: D col=lane&15 (j), row=quad*4+reg (node) ----
#pragma unroll
  for (int jt = 0; jt < 4; jt++) {
#pragma unroll
    for (int reg = 0; reg < 4; reg++) {
      int node = nb * 64 + wv * 16 + quad * 4 + reg;
      if (node < N_NODES)
        out[(size_t)node * HID + jt * 16 + m_n] = acc[jt][reg];
    }
  }
}

// ---------------------------------------------------------------- final linear + log_softmax
// R17: W column in registers (lane j = output j), 64 nodes staged per block,
// 2 nodes in flight per wave (independent fmaf chains). Accumulation order
// per node identical to R16 (i ascending, d=0 start) -> bit-identical.
__global__ __launch_bounds__(256, 2) void final_kernel(
    const float* __restrict__ h, const float* __restrict__ Wout,
    float* __restrict__ out) {
  __shared__ __align__(16) float hs[64 * HID];   // 16 KB
  int t = threadIdx.x;
  int lane = t & 63, wv = t >> 6;
  int nb = blockIdx.x;
  bool jvalid = lane < OUT_FEAT;
  int jc = jvalid ? lane : 0;

  // W column into registers (one-time, 10KB L2-hot; lanes >=40 masked later)
  float wl[HID];
#pragma unroll
  for (int i = 0; i < HID; i++)
    wl[i] = Wout[i * OUT_FEAT + jc];

  // stage 64 nodes' h rows (coalesced float4; tail block reads into acc
  // region of d_ws — safe, unused)
  const float4* hsrc = (const float4*)(h + (size_t)nb * 64 * HID);
  float4* hd = (float4*)hs;
#pragma unroll
  for (int q = 0; q < 4; q++)
    hd[q * 256 + t] = hsrc[q * 256 + t];
  __syncthreads();

  int nwbase = nb * 64 + wv * 16;
  for (int ns = 0; ns < 16; ns += 2) {
    const float* h0 = hs + (wv * 16 + ns) * HID;
    const float* h1 = h0 + HID;
    float d0 = 0.f, d1 = 0.f;
#pragma unroll
    for (int i4 = 0; i4 < 16; i4++) {
      float4 a = *(const float4*)(h0 + i4 * 4);
      float4 b = *(const float4*)(h1 + i4 * 4);
      d0 = fmaf(a.x, wl[i4 * 4 + 0], d0);  d1 = fmaf(b.x, wl[i4 * 4 + 0], d1);
      d0 = fmaf(a.y, wl[i4 * 4 + 1], d0);  d1 = fmaf(b.y, wl[i4 * 4 + 1], d1);
      d0 = fmaf(a.z, wl[i4 * 4 + 2], d0);  d1 = fmaf(b.z, wl[i4 * 4 + 2], d1);
      d0 = fmaf(a.w, wl[i4 * 4 + 3], d0);  d1 = fmaf(b.w, wl[i4 * 4 + 3], d1);
    }
    float m0 = jvalid ? d0 : -1e30f;
    float m1 = jvalid ? d1 : -1e30f;
#pragma unroll
    for (int off = 32; off; off >>= 1) {
      m0 = fmaxf(m0, __shfl_xor(m0, off));
      m1 = fmaxf(m1, __shfl_xor(m1, off));
    }
    float e0 = jvalid ? expf(d0 - m0) : 0.f;
    float e1 = jvalid ? expf(d1 - m1) : 0.f;
    float s0 = e0, s1 = e1;
#pragma unroll
    for (int off = 32; off; off >>= 1) {
      s0 += __shfl_xor(s0, off);
      s1 += __shfl_xor(s1, off);
    }
    float l0 = m0 + logf(s0);
    float l1 = m1 + logf(s1);
    int n0 = nwbase + ns, n1 = n0 + 1;
    if (jvalid) {
      if (n0 < N_NODES) out[(size_t)n0 * OUT_FEAT + lane] = d0 - l0;
      if (n1 < N_NODES) out[(size_t)n1 * OUT_FEAT + lane] = d1 - l1;
    }
  }
}

// ---------------------------------------------------------------- launch
extern "C" void kernel_launch(void* const* d_in, const int* in_sizes, int n_in,
                              void* d_out, int out_size, void* d_ws, size_t ws_size,
                              hipStream_t stream) {
  (void)in_sizes; (void)n_in; (void)out_size; (void)ws_size;
  const float* x    = (const float*)d_in[0];
  const int*   erow = (const int*)d_in[1];
  const int*   ecol = (const int*)d_in[2];
  const float* ew   = (const float*)d_in[3];
  const float* W_in = (const float*)d_in[4];
  const float* b_in = (const float*)d_in[5];
  const float* c1   = (const float*)d_in[6];
  const float* c2   = (const float*)d_in[7];
  const float* Wout = (const float*)d_in[8];
  float* out = (float*)d_out;

  float* h   = (float*)d_ws;
  float* acc = h + NELEM;

  // x buffer (12.8M words, 51.2MB) is consumed by lin_in, then reused:
  unsigned* xw     = (unsigned*)(void*)x;
  unsigned* Brep1  = xw;                     // [0, 32768)
  unsigned* Brep2  = xw + 32768;             // [32768, 65536)
  int*      btail  = (int*)(xw + 65536);     // 98
  int*      rowptr = (int*)(xw + 66048);     // 100001
  uint2*    pack1  = (uint2*)(xw + 262144);  // 98*18432 uint2 (ends 3,874,816)
  uint2*    pack2  = (uint2*)(xw + 3932160); // 1.6M uint2 (ends 7,132,160)

  lin_in_kernel<<<N_NODES / 16, 256, 0, stream>>>(x, W_in, b_in, h);

  repack_kernel<<<128, 256, 0, stream>>>(c1, Brep1);
  repack_kernel<<<128, 256, 0, stream>>>(c2, Brep2);

  binit_kernel<<<1, 128, 0, stream>>>(btail);
  bin_kernel<<<BIN_BLOCKS, 256, 0, stream>>>(erow, ecol, ew, btail, pack1);
  bucket_finalize_kernel<<<NB, 256, 0, stream>>>(btail, pack1, rowptr, pack2);

  spmm_csr_kernel<<<N_NODES / 4, 256, 0, stream>>>(rowptr, pack2, h, acc);
  kan_mfma_kernel<<<(N_NODES + 63) / 64, 256, 0, stream>>>(acc, Brep1, h);

  spmm_csr_kernel<<<N_NODES / 4, 256, 0, stream>>>(rowptr, pack2, h, acc);
  kan_mfma_kernel<<<(N_NODES + 63) / 64, 256, 0, stream>>>(acc, Brep2, h);

  final_kernel<<<(N_NODES + 63) / 64, 256, 0, stream>>>(h, Wout, out);
}

// Round 9
// 435.063 us; speedup vs baseline: 1.4145x; 1.0116x over previous
//
#include <hip/hip_runtime.h>
#include <hip/hip_bf16.h>
#include <string.h>

// KanGNN. Inputs f32 + int32, output f32.
// R19 = R18 with launch fix: final_kernel grid is (N_NODES+63)/64 (64
// nodes/block since R17); R18 accidentally launched N_NODES/4 blocks ->
// 400MB OOB reads -> GPU fault.
// R18: spmm 4x edge unroll (4 gathers in flight/wave; masked slots clamp to
// pack[end-1] with wt=0 -> exact +0; per-lane accumulation order unchanged
// -> bit-identical). pack loads + acc store nontemporal.
// R17: final W-in-registers. R16: kan async global_load_lds dbuf.
// R13/R14: lane-local A build. R11: binned counting-sort CSR build.

#define N_NODES 100000
#define IN_FEAT 128
#define HID 64
#define OUT_FEAT 40
#define NGRID 8
#define N_EDGES 1600000
#define NELEM (N_NODES * HID)

#define NB 98            // buckets: row >> 10
#define CAP 18432        // per-bucket capacity (mean 16384, sigma ~127)
#define BCHUNK 4096      // edges per bin block
#define BIN_BLOCKS ((N_EDGES + BCHUNK - 1) / BCHUNK)   // 391

using short8 = __attribute__((ext_vector_type(8))) short;
using floatx4 = __attribute__((ext_vector_type(4))) float;
using uintx4 = __attribute__((ext_vector_type(4))) unsigned;

// async 16B/lane global->LDS; lds dest = wave-uniform base + lane*16
#define GLOAD_LDS16(gp, lp)                                                   \
  __builtin_amdgcn_global_load_lds(                                           \
      (const __attribute__((address_space(1))) unsigned*)(gp),                \
      (__attribute__((address_space(3))) unsigned*)(lp), 16, 0, 0)

// f32 -> bf16 RNE, packed pair (lo = c, hi = s) — bit-manip form (repack
// path; keeps B coefficient rounding byte-identical to R11..R18)
__device__ __forceinline__ unsigned pack_bf16x2(float c, float s) {
  unsigned uc = __float_as_uint(c);
  unsigned us = __float_as_uint(s);
  uc += 0x7fffu + ((uc >> 16) & 1u);
  us += 0x7fffu + ((us >> 16) & 1u);
  return (uc >> 16) | (us & 0xffff0000u);
}

// same RNE conversion via v_cvt_pk_bf16_f32 (1 instr instead of ~11)
__device__ __forceinline__ unsigned cvtpk_bf16x2(float c, float s) {
  __hip_bfloat162 p = __float22bfloat162_rn(make_float2(c, s));
  unsigned r;
  memcpy(&r, &p, 4);
  return r;
}

// ---------------------------------------------------------------- lin_in
__global__ __launch_bounds__(256) void lin_in_kernel(
    const float* __restrict__ x, const float* __restrict__ W,
    const float* __restrict__ b, float* __restrict__ h) {
  __shared__ __align__(16) float xs[16 * IN_FEAT];   // 8 KB
  int t = threadIdx.x;
  int nb = blockIdx.x;
  const float4* xsrc = (const float4*)(x + (size_t)nb * 16 * IN_FEAT);
  float4* xd = (float4*)xs;
  xd[t] = xsrc[t];
  xd[t + 256] = xsrc[t + 256];
  __syncthreads();
  int lane = t & 63, wv = t >> 6;
  float bj = b[lane];
  float a0 = bj, a1 = bj, a2 = bj, a3 = bj;
  const float* xr = xs + wv * 4 * IN_FEAT;
  const float* Wj = W + lane;
#pragma unroll 4
  for (int i4 = 0; i4 < 32; i4++) {
    float4 x0 = *(const float4*)(xr + 0 * IN_FEAT + i4 * 4);
    float4 x1 = *(const float4*)(xr + 1 * IN_FEAT + i4 * 4);
    float4 x2 = *(const float4*)(xr + 2 * IN_FEAT + i4 * 4);
    float4 x3 = *(const float4*)(xr + 3 * IN_FEAT + i4 * 4);
    float w0 = Wj[(i4 * 4 + 0) * HID];
    float w1 = Wj[(i4 * 4 + 1) * HID];
    float w2 = Wj[(i4 * 4 + 2) * HID];
    float w3 = Wj[(i4 * 4 + 3) * HID];
    a0 = fmaf(x0.x, w0, a0); a0 = fmaf(x0.y, w1, a0); a0 = fmaf(x0.z, w2, a0); a0 = fmaf(x0.w, w3, a0);
    a1 = fmaf(x1.x, w0, a1); a1 = fmaf(x1.y, w1, a1); a1 = fmaf(x1.z, w2, a1); a1 = fmaf(x1.w, w3, a1);
    a2 = fmaf(x2.x, w0, a2); a2 = fmaf(x2.y, w1, a2); a2 = fmaf(x2.z, w2, a2); a2 = fmaf(x2.w, w3, a2);
    a3 = fmaf(x3.x, w0, a3); a3 = fmaf(x3.y, w1, a3); a3 = fmaf(x3.z, w2, a3); a3 = fmaf(x3.w, w3, a3);
  }
  size_t nbase = (size_t)nb * 16 + wv * 4;
  h[(nbase + 0) * HID + lane] = a0;
  h[(nbase + 1) * HID + lane] = a1;
  h[(nbase + 2) * HID + lane] = a2;
  h[(nbase + 3) * HID + lane] = a3;
}

// ---------------------------------------------------------------- CSR build (R11)
__global__ __launch_bounds__(128) void binit_kernel(int* __restrict__ btail) {
  int t = threadIdx.x;
  if (t < NB) btail[t] = t * CAP;
}

// Pass 1: coarse-bucket counting sort.
__global__ __launch_bounds__(256) void bin_kernel(
    const int* __restrict__ row, const int* __restrict__ col,
    const float* __restrict__ w, int* __restrict__ btail,
    uint2* __restrict__ pack1) {
  __shared__ __align__(16) uint2 stage[BCHUNK];   // 32 KB
  __shared__ int bcnt[NB];
  __shared__ int lbase[NB];
  __shared__ int gbase[NB];
  __shared__ int lcur[NB];
  __shared__ int sc[128];
  int t = threadIdx.x;
  int e0 = blockIdx.x * BCHUNK;
  if (t < NB) bcnt[t] = 0;
  __syncthreads();
  int rloc[16];
#pragma unroll
  for (int q = 0; q < 16; q++) {
    int e = e0 + q * 256 + t;
    int r = (e < N_EDGES) ? row[e] : -1;
    rloc[q] = r;
    if (r >= 0) atomicAdd(&bcnt[r >> 10], 1);
  }
  __syncthreads();
  int c = (t < NB) ? bcnt[t] : 0;
  if (t < 128) sc[t] = c;
  __syncthreads();
  int v = c;
#pragma unroll
  for (int off = 1; off < 128; off <<= 1) {
    int add = (t >= off && t < 128) ? sc[t - off] : 0;
    __syncthreads();
    if (t < 128) sc[t] = v = v + add;
    __syncthreads();
  }
  if (t < NB) {
    lbase[t] = v - c;
    lcur[t] = v - c;
    gbase[t] = atomicAdd(&btail[t], c);
  }
  __syncthreads();
#pragma unroll
  for (int q = 0; q < 16; q++) {
    int e = e0 + q * 256 + t;
    int r = rloc[q];
    if (r >= 0) {
      int p = atomicAdd(&lcur[r >> 10], 1);
      unsigned key = ((unsigned)(r & 1023) << 17) | (unsigned)col[e];
      stage[p] = make_uint2(key, __float_as_uint(w[e]));
    }
  }
  __syncthreads();
  int wv = t >> 6, lane = t & 63;
  for (int b = wv; b < NB; b += 4) {
    int len = bcnt[b], src = lbase[b];
    uint2* dst = pack1 + (size_t)gbase[b];
    for (int i = lane; i < len; i += 64)
      dst[i] = stage[src + i];
  }
}

// Pass 2: one block per bucket -> rowptr + exact scatter.
__global__ __launch_bounds__(256) void bucket_finalize_kernel(
    const int* __restrict__ btail, const uint2* __restrict__ pack1,
    int* __restrict__ rowptr, uint2* __restrict__ pack2) {
  __shared__ int rcnt[1024];
  __shared__ int sc[256];
  __shared__ int binfo[2];
  int b = blockIdx.x, t = threadIdx.x;
  if (t < NB) sc[t] = btail[t] - t * CAP;   // per-bucket counts
  rcnt[t] = 0; rcnt[t + 256] = 0; rcnt[t + 512] = 0; rcnt[t + 768] = 0;
  __syncthreads();
  if (t == 0) {
    int base = 0;
    for (int i = 0; i < b; i++) base += sc[i];
    binfo[0] = base;
    binfo[1] = sc[b];
  }
  __syncthreads();
  int base = binfo[0], len = binfo[1];
  const uint2* rec = pack1 + (size_t)b * CAP;
  for (int i = t; i < len; i += 256)
    atomicAdd(&rcnt[rec[i].x >> 17], 1);
  __syncthreads();
  int c0 = rcnt[4 * t], c1 = rcnt[4 * t + 1], c2 = rcnt[4 * t + 2], c3 = rcnt[4 * t + 3];
  int s4 = c0 + c1 + c2 + c3;
  sc[t] = s4;
  __syncthreads();
  int v = s4;
#pragma unroll
  for (int off = 1; off < 256; off <<= 1) {
    int add = (t >= off) ? sc[t - off] : 0;
    __syncthreads();
    sc[t] = v = v + add;
    __syncthreads();
  }
  int excl = v - s4;
  int p0 = base + excl;
  int p1 = p0 + c0, p2 = p1 + c1, p3 = p2 + c2;
  int r0 = (b << 10) + 4 * t;
  if (r0 + 0 < N_NODES) rowptr[r0 + 0] = p0;
  if (r0 + 1 < N_NODES) rowptr[r0 + 1] = p1;
  if (r0 + 2 < N_NODES) rowptr[r0 + 2] = p2;
  if (r0 + 3 < N_NODES) rowptr[r0 + 3] = p3;
  rcnt[4 * t] = p0; rcnt[4 * t + 1] = p1; rcnt[4 * t + 2] = p2; rcnt[4 * t + 3] = p3;
  __syncthreads();
  for (int i = t; i < len; i += 256) {
    uint2 p = rec[i];
    int pos = atomicAdd(&rcnt[p.x >> 17], 1);
    pack2[pos] = make_uint2(p.x & 0x1FFFFu, p.y);
  }
  if (b == NB - 1 && t == 0) rowptr[N_NODES] = N_EDGES;
}

// ---------------------------------------------------------------- spmm (CSR, atomic-free)
// R18: 16 edge-slots per iteration -> 4 gathers in flight per wave.
// Masked slots clamp to pack[end-1] with wt=0 (exact +0). Per-lane
// accumulation order identical to the 1-deep loop -> bit-identical.
__global__ __launch_bounds__(256) void spmm_csr_kernel(
    const int* __restrict__ rowptr, const uint2* __restrict__ pack,
    const float* __restrict__ h, float* __restrict__ acc) {
  int wv = threadIdx.x >> 6, lane = threadIdx.x & 63;
  int n = blockIdx.x * 4 + wv;
  int beg = rowptr[n], end = rowptr[n + 1];
  int slot = lane >> 4, f4 = lane & 15;
  const float4* h4 = (const float4*)h;
  const unsigned long long* packq = (const unsigned long long*)pack;
  float4 v = make_float4(0.f, 0.f, 0.f, 0.f);
  for (int e = beg; e < end; e += 16) {
    int i0 = e + slot, i1 = i0 + 4, i2 = i0 + 8, i3 = i0 + 12;
    int c0 = i0 < end ? i0 : end - 1;
    int c1 = i1 < end ? i1 : end - 1;
    int c2 = i2 < end ? i2 : end - 1;
    int c3 = i3 < end ? i3 : end - 1;
    unsigned long long p0 = __builtin_nontemporal_load(packq + c0);
    unsigned long long p1 = __builtin_nontemporal_load(packq + c1);
    unsigned long long p2 = __builtin_nontemporal_load(packq + c2);
    unsigned long long p3 = __builtin_nontemporal_load(packq + c3);
    float4 h0 = h4[(size_t)(unsigned)p0 * 16 + f4];
    float4 h1 = h4[(size_t)(unsigned)p1 * 16 + f4];
    float4 h2 = h4[(size_t)(unsigned)p2 * 16 + f4];
    float4 h3 = h4[(size_t)(unsigned)p3 * 16 + f4];
    float w0 = (i0 < end) ? __uint_as_float((unsigned)(p0 >> 32)) : 0.f;
    float w1 = (i1 < end) ? __uint_as_float((unsigned)(p1 >> 32)) : 0.f;
    float w2 = (i2 < end) ? __uint_as_float((unsigned)(p2 >> 32)) : 0.f;
    float w3 = (i3 < end) ? __uint_as_float((unsigned)(p3 >> 32)) : 0.f;
    v.x = fmaf(w0, h0.x, v.x); v.y = fmaf(w0, h0.y, v.y);
    v.z = fmaf(w0, h0.z, v.z); v.w = fmaf(w0, h0.w, v.w);
    v.x = fmaf(w1, h1.x, v.x); v.y = fmaf(w1, h1.y, v.y);
    v.z = fmaf(w1, h1.z, v.z); v.w = fmaf(w1, h1.w, v.w);
    v.x = fmaf(w2, h2.x, v.x); v.y = fmaf(w2, h2.y, v.y);
    v.z = fmaf(w2, h2.z, v.z); v.w = fmaf(w2, h2.w, v.w);
    v.x = fmaf(w3, h3.x, v.x); v.y = fmaf(w3, h3.y, v.y);
    v.z = fmaf(w3, h3.z, v.z); v.w = fmaf(w3, h3.w, v.w);
  }
#pragma unroll
  for (int off = 16; off < 64; off <<= 1) {
    v.x += __shfl_xor(v.x, off);
    v.y += __shfl_xor(v.y, off);
    v.z += __shfl_xor(v.z, off);
    v.w += __shfl_xor(v.w, off);
  }
  if (slot == 0) {
    floatx4 vv = {v.x, v.y, v.z, v.w};
    __builtin_nontemporal_store(vv, (floatx4*)acc + (size_t)n * 16 + f4);
  }
}

// ---------------------------------------------------------------- repack
// R16 layout: word idx = ch*8192 + (jt*8+ks)*256 + (quad*16 + m_n)*4 + jj.
// -> each (jt,ks) 1KB block is read by lane=(quad<<4)|m_n at byte lane*16
// (contiguous, conflict-free ds_read_b128); staging is a straight copy.
// Fragment content identical to R14/R15:
//   r = ks>>1, km1 = ((ks&1)<<2)|jj, i = ch*16 + 4*quad + r, j = jt*16+m_n.
__global__ __launch_bounds__(256) void repack_kernel(
    const float* __restrict__ coeffs, unsigned* __restrict__ Brep) {
  int idx = blockIdx.x * 256 + threadIdx.x;   // 32768 words
  int ch = idx >> 13;
  int rem = idx & 8191;
  int blk = rem >> 8;           // jt*8+ks, 0..31
  int jt = blk >> 3, ks = blk & 7;
  int rem2 = rem & 255;
  int ls = rem2 >> 2;           // lane slot = quad*16 + m_n
  int quad = ls >> 4, m_n = ls & 15;
  int jj = rem2 & 3;
  int j = jt * 16 + m_n;
  int r = ks >> 1, km1 = ((ks & 1) << 2) | jj;
  int i = ch * 16 + quad * 4 + r;
  int ws = i * 8 + km1;
  float c0 = coeffs[(size_t)j * 512 + ws];
  float c1 = coeffs[32768 + (size_t)j * 512 + ws];
  Brep[idx] = pack_bf16x2(c0, c1);
}

// ---------------------------------------------------------------- KAN via MFMA
// (B via async global_load_lds, double-buffered 16KB half-slices)
__global__ __launch_bounds__(256, 4) void kan_mfma_kernel(
    const float* __restrict__ s, const unsigned* __restrict__ Brep,
    float* __restrict__ out) {
  __shared__ __align__(16) unsigned Bs[2][4096];   // 2 x 16 KB
  int t = threadIdx.x;
  int lane = t & 63;
  int wv = t >> 6;
  int nb = blockIdx.x;

  int m_n = lane & 15;            // A row within 16x16 tile
  int quad = lane >> 4;           // k-quad of the MFMA fragment
  int node_sub = wv * 16 + m_n;
  int n_row = nb * 64 + node_sub;
  bool rvalid = (n_row < N_NODES);

  const char* Gb = (const char*)Brep;   // 8 halves x 16KB, linear

  // issue half 0 (4 x 1KB chunks per wave; chunk c = i*4 + wv)
#pragma unroll
  for (int i = 0; i < 4; i++) {
    int c = i * 4 + wv;
    GLOAD_LDS16(Gb + c * 1024 + lane * 16, (char*)&Bs[0][0] + c * 1024);
  }

  // prefetch all 4 chunks' s-vectors (i = ch*16 + quad*4 + r)
  float4 sv[4];
#pragma unroll
  for (int ch = 0; ch < 4; ch++) {
    sv[ch] = rvalid
      ? *reinterpret_cast<const float4*>(s + (size_t)n_row * HID + ch * 16 + quad * 4)
      : make_float4(0.f, 0.f, 0.f, 0.f);
  }

  floatx4 acc[4];
#pragma unroll
  for (int jt = 0; jt < 4; jt++) acc[jt] = (floatx4){0.f, 0.f, 0.f, 0.f};

  short8 afr[8];

#pragma unroll
  for (int h = 0; h < 8; h++) {
    // drain this half's loads (and prior LDS reads), sync all waves
    asm volatile("s_waitcnt vmcnt(0)" ::: "memory");
    __syncthreads();

    // issue next half into the other buffer (safe: its last readers
    // finished before the barrier above); latency hides under build+MFMA
    if (h < 7) {
      const char* gsrc = Gb + (h + 1) * 16384;
      char* ldst = (char*)&Bs[(h + 1) & 1][0];
#pragma unroll
      for (int i = 0; i < 4; i++) {
        int c = i * 4 + wv;
        GLOAD_LDS16(gsrc + c * 1024 + lane * 16, ldst + c * 1024);
      }
    }

    // build A fragments at the start of each ch (even h); reused by odd h
    if ((h & 1) == 0) {
      int ch = h >> 1;
      float ss[4] = {sv[ch].x, sv[ch].y, sv[ch].z, sv[ch].w};
#pragma unroll
      for (int r = 0; r < 4; r++) {
        float s1, c1;
        __sincosf(ss[r], &s1, &c1);
        float ck = c1, sk = s1;
        unsigned wbuf[8];
#pragma unroll
        for (int km1 = 0; km1 < 8; km1++) {
          wbuf[km1] = cvtpk_bf16x2(ck, sk);
          float cn = fmaf(ck, c1, -sk * s1);
          float sn = fmaf(sk, c1, ck * s1);
          ck = cn; sk = sn;
        }
        uintx4 lo = (uintx4){wbuf[0], wbuf[1], wbuf[2], wbuf[3]};
        uintx4 hi = (uintx4){wbuf[4], wbuf[5], wbuf[6], wbuf[7]};
        memcpy(&afr[2 * r], &lo, 16);
        memcpy(&afr[2 * r + 1], &hi, 16);
      }
    }

    // ---- MFMA from LDS: lane reads at lane*16 within each 1KB block ----
    const char* Bb = (const char*)&Bs[h & 1][0];
    int jtp = (h & 1) * 2;
#pragma unroll
    for (int ks = 0; ks < 8; ks++) {
      short8 af = afr[ks];
#pragma unroll
      for (int j2 = 0; j2 < 2; j2++) {
        short8 bf = *reinterpret_cast<const short8*>(Bb + (j2 * 8 + ks) * 1024 + lane * 16);
        acc[jtp + j2] = __builtin_amdgcn_mfma_f32_16x16x32_bf16(af, bf, acc[jtp + j2], 0, 0, 0);
      }
    }
  }

  // ---- epilogue: D col=lane&15 (j), row=quad*4+reg (node) ----
#pragma unroll
  for (int jt = 0; jt < 4; jt++) {
#pragma unroll
    for (int reg = 0; reg < 4; reg++) {
      int node = nb * 64 + wv * 16 + quad * 4 + reg;
      if (node < N_NODES)
        out[(size_t)node * HID + jt * 16 + m_n] = acc[jt][reg];
    }
  }
}

// ---------------------------------------------------------------- final linear + log_softmax
// R17: W column in registers (lane j = output j), 64 nodes staged per block,
// 2 nodes in flight per wave (independent fmaf chains). Accumulation order
// per node identical to R16 (i ascending, d=0 start) -> bit-identical.
__global__ __launch_bounds__(256, 2) void final_kernel(
    const float* __restrict__ h, const float* __restrict__ Wout,
    float* __restrict__ out) {
  __shared__ __align__(16) float hs[64 * HID];   // 16 KB
  int t = threadIdx.x;
  int lane = t & 63, wv = t >> 6;
  int nb = blockIdx.x;
  bool jvalid = lane < OUT_FEAT;
  int jc = jvalid ? lane : 0;

  // W column into registers (one-time, 10KB L2-hot; lanes >=40 masked later)
  float wl[HID];
#pragma unroll
  for (int i = 0; i < HID; i++)
    wl[i] = Wout[i * OUT_FEAT + jc];

  // stage 64 nodes' h rows (coalesced float4; tail block reads into acc
  // region of d_ws — safe, unused)
  const float4* hsrc = (const float4*)(h + (size_t)nb * 64 * HID);
  float4* hd = (float4*)hs;
#pragma unroll
  for (int q = 0; q < 4; q++)
    hd[q * 256 + t] = hsrc[q * 256 + t];
  __syncthreads();

  int nwbase = nb * 64 + wv * 16;
  for (int ns = 0; ns < 16; ns += 2) {
    const float* h0 = hs + (wv * 16 + ns) * HID;
    const float* h1 = h0 + HID;
    float d0 = 0.f, d1 = 0.f;
#pragma unroll
    for (int i4 = 0; i4 < 16; i4++) {
      float4 a = *(const float4*)(h0 + i4 * 4);
      float4 b = *(const float4*)(h1 + i4 * 4);
      d0 = fmaf(a.x, wl[i4 * 4 + 0], d0);  d1 = fmaf(b.x, wl[i4 * 4 + 0], d1);
      d0 = fmaf(a.y, wl[i4 * 4 + 1], d0);  d1 = fmaf(b.y, wl[i4 * 4 + 1], d1);
      d0 = fmaf(a.z, wl[i4 * 4 + 2], d0);  d1 = fmaf(b.z, wl[i4 * 4 + 2], d1);
      d0 = fmaf(a.w, wl[i4 * 4 + 3], d0);  d1 = fmaf(b.w, wl[i4 * 4 + 3], d1);
    }
    float m0 = jvalid ? d0 : -1e30f;
    float m1 = jvalid ? d1 : -1e30f;
#pragma unroll
    for (int off = 32; off; off >>= 1) {
      m0 = fmaxf(m0, __shfl_xor(m0, off));
      m1 = fmaxf(m1, __shfl_xor(m1, off));
    }
    float e0 = jvalid ? expf(d0 - m0) : 0.f;
    float e1 = jvalid ? expf(d1 - m1) : 0.f;
    float s0 = e0, s1 = e1;
#pragma unroll
    for (int off = 32; off; off >>= 1) {
      s0 += __shfl_xor(s0, off);
      s1 += __shfl_xor(s1, off);
    }
    float l0 = m0 + logf(s0);
    float l1 = m1 + logf(s1);
    int n0 = nwbase + ns, n1 = n0 + 1;
    if (jvalid) {
      if (n0 < N_NODES) out[(size_t)n0 * OUT_FEAT + lane] = d0 - l0;
      if (n1 < N_NODES) out[(size_t)n1 * OUT_FEAT + lane] = d1 - l1;
    }
  }
}

// ---------------------------------------------------------------- launch
extern "C" void kernel_launch(void* const* d_in, const int* in_sizes, int n_in,
                              void* d_out, int out_size, void* d_ws, size_t ws_size,
                              hipStream_t stream) {
  (void)in_sizes; (void)n_in; (void)out_size; (void)ws_size;
  const float* x    = (const float*)d_in[0];
  const int*   erow = (const int*)d_in[1];
  const int*   ecol = (const int*)d_in[2];
  const float* ew   = (const float*)d_in[3];
  const float* W_in = (const float*)d_in[4];
  const float* b_in = (const float*)d_in[5];
  const float* c1   = (const float*)d_in[6];
  const float* c2   = (const float*)d_in[7];
  const float* Wout = (const float*)d_in[8];
  float* out = (float*)d_out;

  float* h   = (float*)d_ws;
  float* acc = h + NELEM;

  // x buffer (12.8M words, 51.2MB) is consumed by lin_in, then reused:
  unsigned* xw     = (unsigned*)(void*)x;
  unsigned* Brep1  = xw;                     // [0, 32768)
  unsigned* Brep2  = xw + 32768;             // [32768, 65536)
  int*      btail  = (int*)(xw + 65536);     // 98
  int*      rowptr = (int*)(xw + 66048);     // 100001
  uint2*    pack1  = (uint2*)(xw + 262144);  // 98*18432 uint2 (ends 3,874,816)
  uint2*    pack2  = (uint2*)(xw + 3932160); // 1.6M uint2 (ends 7,132,160)

  lin_in_kernel<<<N_NODES / 16, 256, 0, stream>>>(x, W_in, b_in, h);

  repack_kernel<<<128, 256, 0, stream>>>(c1, Brep1);
  repack_kernel<<<128, 256, 0, stream>>>(c2, Brep2);

  binit_kernel<<<1, 128, 0, stream>>>(btail);
  bin_kernel<<<BIN_BLOCKS, 256, 0, stream>>>(erow, ecol, ew, btail, pack1);
  bucket_finalize_kernel<<<NB, 256, 0, stream>>>(btail, pack1, rowptr, pack2);

  spmm_csr_kernel<<<N_NODES / 4, 256, 0, stream>>>(rowptr, pack2, h, acc);
  kan_mfma_kernel<<<(N_NODES + 63) / 64, 256, 0, stream>>>(acc, Brep1, h);

  spmm_csr_kernel<<<N_NODES / 4, 256, 0, stream>>>(rowptr, pack2, h, acc);
  kan_mfma_kernel<<<(N_NODES + 63) / 64, 256, 0, stream>>>(acc, Brep2, h);

  final_kernel<<<(N_NODES + 63) / 64, 256, 0, stream>>>(h, Wout, out);
}

// Round 10
// 425.370 us; speedup vs baseline: 1.4467x; 1.0228x over previous
//
#include <hip/hip_runtime.h>
#include <hip/hip_bf16.h>
#include <string.h>

// KanGNN. Inputs f32 + int32, output f32.
// R20: fuse spmm+kan (and final into the 2nd pair). spmm is at the random-
// gather BW floor (R19: 4x MLP -> only 1.11x; 181MB @ 3.6TB/s); remaining
// win is cross-kernel: resident blocks overlap gather-phase and MFMA-phase,
// the 25MB acc roundtrip disappears, B-staging hides under gathers, and
// final's h roundtrip disappears. Ping-pong h0->h1 avoids the cross-block
// gather/write race (kan writes a DIFFERENT buffer than the one gathered).
// Per-value math order identical to R19 -> bit-identical output.
// R18/19: spmm 4x edge unroll. R17: final W-in-registers. R16: kan async
// global_load_lds dbuf. R13/14: lane-local A build. R11: binned CSR build.

#define N_NODES 100000
#define IN_FEAT 128
#define HID 64
#define OUT_FEAT 40
#define NGRID 8
#define N_EDGES 1600000
#define NELEM (N_NODES * HID)

#define NB 98            // buckets: row >> 10
#define CAP 18432        // per-bucket capacity (mean 16384, sigma ~127)
#define BCHUNK 4096      // edges per bin block
#define BIN_BLOCKS ((N_EDGES + BCHUNK - 1) / BCHUNK)   // 391

using short8 = __attribute__((ext_vector_type(8))) short;
using floatx4 = __attribute__((ext_vector_type(4))) float;
using uintx4 = __attribute__((ext_vector_type(4))) unsigned;

// async 16B/lane global->LDS; lds dest = wave-uniform base + lane*16
#define GLOAD_LDS16(gp, lp)                                                   \
  __builtin_amdgcn_global_load_lds(                                           \
      (const __attribute__((address_space(1))) unsigned*)(gp),                \
      (__attribute__((address_space(3))) unsigned*)(lp), 16, 0, 0)

// f32 -> bf16 RNE, packed pair (lo = c, hi = s) — bit-manip form (repack
// path; keeps B coefficient rounding byte-identical to R11..R19)
__device__ __forceinline__ unsigned pack_bf16x2(float c, float s) {
  unsigned uc = __float_as_uint(c);
  unsigned us = __float_as_uint(s);
  uc += 0x7fffu + ((uc >> 16) & 1u);
  us += 0x7fffu + ((us >> 16) & 1u);
  return (uc >> 16) | (us & 0xffff0000u);
}

// same RNE conversion via v_cvt_pk_bf16_f32 (1 instr instead of ~11)
__device__ __forceinline__ unsigned cvtpk_bf16x2(float c, float s) {
  __hip_bfloat162 p = __float22bfloat162_rn(make_float2(c, s));
  unsigned r;
  memcpy(&r, &p, 4);
  return r;
}

// ---------------------------------------------------------------- lin_in
__global__ __launch_bounds__(256) void lin_in_kernel(
    const float* __restrict__ x, const float* __restrict__ W,
    const float* __restrict__ b, float* __restrict__ h) {
  __shared__ __align__(16) float xs[16 * IN_FEAT];   // 8 KB
  int t = threadIdx.x;
  int nb = blockIdx.x;
  const float4* xsrc = (const float4*)(x + (size_t)nb * 16 * IN_FEAT);
  float4* xd = (float4*)xs;
  xd[t] = xsrc[t];
  xd[t + 256] = xsrc[t + 256];
  __syncthreads();
  int lane = t & 63, wv = t >> 6;
  float bj = b[lane];
  float a0 = bj, a1 = bj, a2 = bj, a3 = bj;
  const float* xr = xs + wv * 4 * IN_FEAT;
  const float* Wj = W + lane;
#pragma unroll 4
  for (int i4 = 0; i4 < 32; i4++) {
    float4 x0 = *(const float4*)(xr + 0 * IN_FEAT + i4 * 4);
    float4 x1 = *(const float4*)(xr + 1 * IN_FEAT + i4 * 4);
    float4 x2 = *(const float4*)(xr + 2 * IN_FEAT + i4 * 4);
    float4 x3 = *(const float4*)(xr + 3 * IN_FEAT + i4 * 4);
    float w0 = Wj[(i4 * 4 + 0) * HID];
    float w1 = Wj[(i4 * 4 + 1) * HID];
    float w2 = Wj[(i4 * 4 + 2) * HID];
    float w3 = Wj[(i4 * 4 + 3) * HID];
    a0 = fmaf(x0.x, w0, a0); a0 = fmaf(x0.y, w1, a0); a0 = fmaf(x0.z, w2, a0); a0 = fmaf(x0.w, w3, a0);
    a1 = fmaf(x1.x, w0, a1); a1 = fmaf(x1.y, w1, a1); a1 = fmaf(x1.z, w2, a1); a1 = fmaf(x1.w, w3, a1);
    a2 = fmaf(x2.x, w0, a2); a2 = fmaf(x2.y, w1, a2); a2 = fmaf(x2.z, w2, a2); a2 = fmaf(x2.w, w3, a2);
    a3 = fmaf(x3.x, w0, a3); a3 = fmaf(x3.y, w1, a3); a3 = fmaf(x3.z, w2, a3); a3 = fmaf(x3.w, w3, a3);
  }
  size_t nbase = (size_t)nb * 16 + wv * 4;
  h[(nbase + 0) * HID + lane] = a0;
  h[(nbase + 1) * HID + lane] = a1;
  h[(nbase + 2) * HID + lane] = a2;
  h[(nbase + 3) * HID + lane] = a3;
}

// ---------------------------------------------------------------- CSR build (R11)
__global__ __launch_bounds__(128) void binit_kernel(int* __restrict__ btail) {
  int t = threadIdx.x;
  if (t < NB) btail[t] = t * CAP;
}

// Pass 1: coarse-bucket counting sort.
__global__ __launch_bounds__(256) void bin_kernel(
    const int* __restrict__ row, const int* __restrict__ col,
    const float* __restrict__ w, int* __restrict__ btail,
    uint2* __restrict__ pack1) {
  __shared__ __align__(16) uint2 stage[BCHUNK];   // 32 KB
  __shared__ int bcnt[NB];
  __shared__ int lbase[NB];
  __shared__ int gbase[NB];
  __shared__ int lcur[NB];
  __shared__ int sc[128];
  int t = threadIdx.x;
  int e0 = blockIdx.x * BCHUNK;
  if (t < NB) bcnt[t] = 0;
  __syncthreads();
  int rloc[16];
#pragma unroll
  for (int q = 0; q < 16; q++) {
    int e = e0 + q * 256 + t;
    int r = (e < N_EDGES) ? row[e] : -1;
    rloc[q] = r;
    if (r >= 0) atomicAdd(&bcnt[r >> 10], 1);
  }
  __syncthreads();
  int c = (t < NB) ? bcnt[t] : 0;
  if (t < 128) sc[t] = c;
  __syncthreads();
  int v = c;
#pragma unroll
  for (int off = 1; off < 128; off <<= 1) {
    int add = (t >= off && t < 128) ? sc[t - off] : 0;
    __syncthreads();
    if (t < 128) sc[t] = v = v + add;
    __syncthreads();
  }
  if (t < NB) {
    lbase[t] = v - c;
    lcur[t] = v - c;
    gbase[t] = atomicAdd(&btail[t], c);
  }
  __syncthreads();
#pragma unroll
  for (int q = 0; q < 16; q++) {
    int e = e0 + q * 256 + t;
    int r = rloc[q];
    if (r >= 0) {
      int p = atomicAdd(&lcur[r >> 10], 1);
      unsigned key = ((unsigned)(r & 1023) << 17) | (unsigned)col[e];
      stage[p] = make_uint2(key, __float_as_uint(w[e]));
    }
  }
  __syncthreads();
  int wv = t >> 6, lane = t & 63;
  for (int b = wv; b < NB; b += 4) {
    int len = bcnt[b], src = lbase[b];
    uint2* dst = pack1 + (size_t)gbase[b];
    for (int i = lane; i < len; i += 64)
      dst[i] = stage[src + i];
  }
}

// Pass 2: one block per bucket -> rowptr + exact scatter.
__global__ __launch_bounds__(256) void bucket_finalize_kernel(
    const int* __restrict__ btail, const uint2* __restrict__ pack1,
    int* __restrict__ rowptr, uint2* __restrict__ pack2) {
  __shared__ int rcnt[1024];
  __shared__ int sc[256];
  __shared__ int binfo[2];
  int b = blockIdx.x, t = threadIdx.x;
  if (t < NB) sc[t] = btail[t] - t * CAP;   // per-bucket counts
  rcnt[t] = 0; rcnt[t + 256] = 0; rcnt[t + 512] = 0; rcnt[t + 768] = 0;
  __syncthreads();
  if (t == 0) {
    int base = 0;
    for (int i = 0; i < b; i++) base += sc[i];
    binfo[0] = base;
    binfo[1] = sc[b];
  }
  __syncthreads();
  int base = binfo[0], len = binfo[1];
  const uint2* rec = pack1 + (size_t)b * CAP;
  for (int i = t; i < len; i += 256)
    atomicAdd(&rcnt[rec[i].x >> 17], 1);
  __syncthreads();
  int c0 = rcnt[4 * t], c1 = rcnt[4 * t + 1], c2 = rcnt[4 * t + 2], c3 = rcnt[4 * t + 3];
  int s4 = c0 + c1 + c2 + c3;
  sc[t] = s4;
  __syncthreads();
  int v = s4;
#pragma unroll
  for (int off = 1; off < 256; off <<= 1) {
    int add = (t >= off) ? sc[t - off] : 0;
    __syncthreads();
    sc[t] = v = v + add;
    __syncthreads();
  }
  int excl = v - s4;
  int p0 = base + excl;
  int p1 = p0 + c0, p2 = p1 + c1, p3 = p2 + c2;
  int r0 = (b << 10) + 4 * t;
  if (r0 + 0 < N_NODES) rowptr[r0 + 0] = p0;
  if (r0 + 1 < N_NODES) rowptr[r0 + 1] = p1;
  if (r0 + 2 < N_NODES) rowptr[r0 + 2] = p2;
  if (r0 + 3 < N_NODES) rowptr[r0 + 3] = p3;
  rcnt[4 * t] = p0; rcnt[4 * t + 1] = p1; rcnt[4 * t + 2] = p2; rcnt[4 * t + 3] = p3;
  __syncthreads();
  for (int i = t; i < len; i += 256) {
    uint2 p = rec[i];
    int pos = atomicAdd(&rcnt[p.x >> 17], 1);
    pack2[pos] = make_uint2(p.x & 0x1FFFFu, p.y);
  }
  if (b == NB - 1 && t == 0) rowptr[N_NODES] = N_EDGES;
}

// ---------------------------------------------------------------- repack
// R16 layout: word idx = ch*8192 + (jt*8+ks)*256 + (quad*16 + m_n)*4 + jj.
// Quarter (ch,jt) = contiguous 8KB; each (jt,ks) 1KB block read at lane*16.
__global__ __launch_bounds__(256) void repack_kernel(
    const float* __restrict__ coeffs, unsigned* __restrict__ Brep) {
  int idx = blockIdx.x * 256 + threadIdx.x;   // 32768 words
  int ch = idx >> 13;
  int rem = idx & 8191;
  int blk = rem >> 8;           // jt*8+ks, 0..31
  int jt = blk >> 3, ks = blk & 7;
  int rem2 = rem & 255;
  int ls = rem2 >> 2;           // lane slot = quad*16 + m_n
  int quad = ls >> 4, m_n = ls & 15;
  int jj = rem2 & 3;
  int j = jt * 16 + m_n;
  int r = ks >> 1, km1 = ((ks & 1) << 2) | jj;
  int i = ch * 16 + quad * 4 + r;
  int ws = i * 8 + km1;
  float c0 = coeffs[(size_t)j * 512 + ws];
  float c1 = coeffs[32768 + (size_t)j * 512 + ws];
  Brep[idx] = pack_bf16x2(c0, c1);
}

// ---------------------------------------------------------------- fused spmm + KAN (+ final)
// 64 nodes/block, 4 waves. Phase 1: each wave spmm-gathers its 16 rows
// (R19's 4-slot x4-unroll loop) into LDS s_tile. Phase 2: KAN per R16 but
// B staged as 16 quarter-slices (8KB dbuf halves; quarter q: ch=q>>2,
// jt=q&3; MFMA order per acc[jt] = ch0..3 x ks0..7 == R16's order ->
// bit-identical). Quarter 0 issued at kernel entry (hides under gathers).
// DO_FINAL: kan acc -> s_tile -> R17 final phase (W columns in registers).
template <int DO_FINAL>
__global__ __launch_bounds__(256, 4) void fused_spmm_kan_kernel(
    const int* __restrict__ rowptr, const uint2* __restrict__ pack,
    const float* __restrict__ hin, const unsigned* __restrict__ Brep,
    float* __restrict__ outp, const float* __restrict__ Wout) {
  __shared__ __align__(16) unsigned Bs[2][2048];   // 2 x 8 KB
  __shared__ __align__(16) float s_tile[64 * 64];  // 16 KB
  int t = threadIdx.x;
  int lane = t & 63, wv = t >> 6;
  int nb = blockIdx.x;
  const char* Gb = (const char*)Brep;

  // issue quarter 0 (ch0,jt0) staging now; latency hides under the gathers
#pragma unroll
  for (int i = 0; i < 2; i++) {
    int c = wv + 4 * i;
    GLOAD_LDS16(Gb + c * 1024 + lane * 16, (char*)&Bs[0][0] + c * 1024);
  }

  // ---- phase 1: spmm for rows nb*64 + wv*16 + 0..15 ----
  {
    int rpi = nb * 64 + wv * 16 + lane;
    int rp = 0;
    if (lane < 17) rp = rowptr[rpi < N_NODES ? rpi : N_NODES];  // rowptr[N]=E
    int slot = lane >> 4, f4 = lane & 15;
    const float4* h4 = (const float4*)hin;
    const unsigned long long* packq = (const unsigned long long*)pack;
    for (int i = 0; i < 16; i++) {
      int beg = __shfl(rp, i), end = __shfl(rp, i + 1);
      float4 v = make_float4(0.f, 0.f, 0.f, 0.f);
      for (int e = beg; e < end; e += 16) {
        int i0 = e + slot, i1 = i0 + 4, i2 = i0 + 8, i3 = i0 + 12;
        int c0 = i0 < end ? i0 : end - 1;
        int c1 = i1 < end ? i1 : end - 1;
        int c2 = i2 < end ? i2 : end - 1;
        int c3 = i3 < end ? i3 : end - 1;
        unsigned long long p0 = __builtin_nontemporal_load(packq + c0);
        unsigned long long p1 = __builtin_nontemporal_load(packq + c1);
        unsigned long long p2 = __builtin_nontemporal_load(packq + c2);
        unsigned long long p3 = __builtin_nontemporal_load(packq + c3);
        float4 h0 = h4[(size_t)(unsigned)p0 * 16 + f4];
        float4 h1 = h4[(size_t)(unsigned)p1 * 16 + f4];
        float4 h2 = h4[(size_t)(unsigned)p2 * 16 + f4];
        float4 h3 = h4[(size_t)(unsigned)p3 * 16 + f4];
        float w0 = (i0 < end) ? __uint_as_float((unsigned)(p0 >> 32)) : 0.f;
        float w1 = (i1 < end) ? __uint_as_float((unsigned)(p1 >> 32)) : 0.f;
        float w2 = (i2 < end) ? __uint_as_float((unsigned)(p2 >> 32)) : 0.f;
        float w3 = (i3 < end) ? __uint_as_float((unsigned)(p3 >> 32)) : 0.f;
        v.x = fmaf(w0, h0.x, v.x); v.y = fmaf(w0, h0.y, v.y);
        v.z = fmaf(w0, h0.z, v.z); v.w = fmaf(w0, h0.w, v.w);
        v.x = fmaf(w1, h1.x, v.x); v.y = fmaf(w1, h1.y, v.y);
        v.z = fmaf(w1, h1.z, v.z); v.w = fmaf(w1, h1.w, v.w);
        v.x = fmaf(w2, h2.x, v.x); v.y = fmaf(w2, h2.y, v.y);
        v.z = fmaf(w2, h2.z, v.z); v.w = fmaf(w2, h2.w, v.w);
        v.x = fmaf(w3, h3.x, v.x); v.y = fmaf(w3, h3.y, v.y);
        v.z = fmaf(w3, h3.z, v.z); v.w = fmaf(w3, h3.w, v.w);
      }
#pragma unroll
      for (int off = 16; off < 64; off <<= 1) {
        v.x += __shfl_xor(v.x, off);
        v.y += __shfl_xor(v.y, off);
        v.z += __shfl_xor(v.z, off);
        v.w += __shfl_xor(v.w, off);
      }
      if (slot == 0)
        *(float4*)&s_tile[(wv * 16 + i) * 64 + f4 * 4] = v;
    }
  }
  __syncthreads();   // s_tile complete

  // ---- phase 2: KAN ----
  int m_n = lane & 15, quad = lane >> 4;
  int node_sub = wv * 16 + m_n;
  float4 sv[4];
#pragma unroll
  for (int ch = 0; ch < 4; ch++)
    sv[ch] = *(const float4*)&s_tile[node_sub * 64 + ch * 16 + quad * 4];

  floatx4 acc[4];
#pragma unroll
  for (int jt = 0; jt < 4; jt++) acc[jt] = (floatx4){0.f, 0.f, 0.f, 0.f};
  short8 afr[8];

#pragma unroll
  for (int q = 0; q < 16; q++) {
    // drain this quarter's staging loads; all waves sync (buffer q&1 ready,
    // and everyone is past reading buffer (q+1)&1 from quarter q-1)
    asm volatile("s_waitcnt vmcnt(0)" ::: "memory");
    __syncthreads();
    if (q < 15) {
      int qq = q + 1;
      const char* gsrc = Gb + (qq >> 2) * 32768 + (qq & 3) * 8192;
      char* ldst = (char*)&Bs[qq & 1][0];
#pragma unroll
      for (int i = 0; i < 2; i++) {
        int c = wv + 4 * i;
        GLOAD_LDS16(gsrc + c * 1024 + lane * 16, ldst + c * 1024);
      }
    }
    if ((q & 3) == 0) {   // build A fragments at the start of each ch
      int ch = q >> 2;
      float ss[4] = {sv[ch].x, sv[ch].y, sv[ch].z, sv[ch].w};
#pragma unroll
      for (int r = 0; r < 4; r++) {
        float s1, c1;
        __sincosf(ss[r], &s1, &c1);
        float ck = c1, sk = s1;
        unsigned wbuf[8];
#pragma unroll
        for (int km1 = 0; km1 < 8; km1++) {
          wbuf[km1] = cvtpk_bf16x2(ck, sk);
          float cn = fmaf(ck, c1, -sk * s1);
          float sn = fmaf(sk, c1, ck * s1);
          ck = cn; sk = sn;
        }
        uintx4 lo = (uintx4){wbuf[0], wbuf[1], wbuf[2], wbuf[3]};
        uintx4 hi = (uintx4){wbuf[4], wbuf[5], wbuf[6], wbuf[7]};
        memcpy(&afr[2 * r], &lo, 16);
        memcpy(&afr[2 * r + 1], &hi, 16);
      }
    }
    const char* Bb = (const char*)&Bs[q & 1][0];
    int jt = q & 3;
#pragma unroll
    for (int ks = 0; ks < 8; ks++) {
      short8 bf = *reinterpret_cast<const short8*>(Bb + ks * 1024 + lane * 16);
      acc[jt] = __builtin_amdgcn_mfma_f32_16x16x32_bf16(afr[ks], bf, acc[jt], 0, 0, 0);
    }
  }

  if (DO_FINAL == 0) {
    // epilogue: D col=m_n (j), row=quad*4+reg (node) -> h_out global
#pragma unroll
    for (int jt = 0; jt < 4; jt++) {
#pragma unroll
      for (int reg = 0; reg < 4; reg++) {
        int node = nb * 64 + wv * 16 + quad * 4 + reg;
        if (node < N_NODES)
          outp[(size_t)node * HID + jt * 16 + m_n] = acc[jt][reg];
      }
    }
  } else {
    // acc -> s_tile (s_tile dead since sv prefetch; own-wave rows only)
#pragma unroll
    for (int jt = 0; jt < 4; jt++) {
#pragma unroll
      for (int reg = 0; reg < 4; reg++)
        s_tile[(wv * 16 + quad * 4 + reg) * 64 + jt * 16 + m_n] = acc[jt][reg];
    }
    __syncthreads();
    // ---- final phase (R17): W column in registers, 2 nodes in flight ----
    bool jvalid = lane < OUT_FEAT;
    int jc = jvalid ? lane : 0;
    float wl[HID];
#pragma unroll
    for (int i2 = 0; i2 < HID; i2++)
      wl[i2] = Wout[i2 * OUT_FEAT + jc];
    int nwbase = nb * 64 + wv * 16;
    for (int ns = 0; ns < 16; ns += 2) {
      const float* h0p = &s_tile[(wv * 16 + ns) * 64];
      const float* h1p = h0p + 64;
      float d0 = 0.f, d1 = 0.f;
#pragma unroll
      for (int i4 = 0; i4 < 16; i4++) {
        float4 a = *(const float4*)(h0p + i4 * 4);
        float4 b = *(const float4*)(h1p + i4 * 4);
        d0 = fmaf(a.x, wl[i4 * 4 + 0], d0);  d1 = fmaf(b.x, wl[i4 * 4 + 0], d1);
        d0 = fmaf(a.y, wl[i4 * 4 + 1], d0);  d1 = fmaf(b.y, wl[i4 * 4 + 1], d1);
        d0 = fmaf(a.z, wl[i4 * 4 + 2], d0);  d1 = fmaf(b.z, wl[i4 * 4 + 2], d1);
        d0 = fmaf(a.w, wl[i4 * 4 + 3], d0);  d1 = fmaf(b.w, wl[i4 * 4 + 3], d1);
      }
      float m0 = jvalid ? d0 : -1e30f;
      float m1 = jvalid ? d1 : -1e30f;
#pragma unroll
      for (int off = 32; off; off >>= 1) {
        m0 = fmaxf(m0, __shfl_xor(m0, off));
        m1 = fmaxf(m1, __shfl_xor(m1, off));
      }
      float e0 = jvalid ? expf(d0 - m0) : 0.f;
      float e1 = jvalid ? expf(d1 - m1) : 0.f;
      float s0 = e0, s1 = e1;
#pragma unroll
      for (int off = 32; off; off >>= 1) {
        s0 += __shfl_xor(s0, off);
        s1 += __shfl_xor(s1, off);
      }
      float l0 = m0 + logf(s0);
      float l1 = m1 + logf(s1);
      int n0 = nwbase + ns, n1 = n0 + 1;
      if (jvalid) {
        if (n0 < N_NODES) outp[(size_t)n0 * OUT_FEAT + lane] = d0 - l0;
        if (n1 < N_NODES) outp[(size_t)n1 * OUT_FEAT + lane] = d1 - l1;
      }
    }
  }
}

// ---------------------------------------------------------------- launch
extern "C" void kernel_launch(void* const* d_in, const int* in_sizes, int n_in,
                              void* d_out, int out_size, void* d_ws, size_t ws_size,
                              hipStream_t stream) {
  (void)in_sizes; (void)n_in; (void)out_size; (void)ws_size;
  const float* x    = (const float*)d_in[0];
  const int*   erow = (const int*)d_in[1];
  const int*   ecol = (const int*)d_in[2];
  const float* ew   = (const float*)d_in[3];
  const float* W_in = (const float*)d_in[4];
  const float* b_in = (const float*)d_in[5];
  const float* c1   = (const float*)d_in[6];
  const float* c2   = (const float*)d_in[7];
  const float* Wout = (const float*)d_in[8];
  float* out = (float*)d_out;

  float* h0 = (float*)d_ws;          // lin_in output / fused1 gather source
  float* h1 = h0 + NELEM;            // fused1 output / fused2 gather source

  // x buffer (12.8M words, 51.2MB) is consumed by lin_in, then reused:
  unsigned* xw     = (unsigned*)(void*)x;
  unsigned* Brep1  = xw;                     // [0, 32768)
  unsigned* Brep2  = xw + 32768;             // [32768, 65536)
  int*      btail  = (int*)(xw + 65536);     // 98
  int*      rowptr = (int*)(xw + 66048);     // 100001
  uint2*    pack1  = (uint2*)(xw + 262144);  // 98*18432 uint2 (ends 3,874,816)
  uint2*    pack2  = (uint2*)(xw + 3932160); // 1.6M uint2 (ends 7,132,160)

  const int fgrid = (N_NODES + 63) / 64;     // 1563

  lin_in_kernel<<<N_NODES / 16, 256, 0, stream>>>(x, W_in, b_in, h0);

  repack_kernel<<<128, 256, 0, stream>>>(c1, Brep1);
  repack_kernel<<<128, 256, 0, stream>>>(c2, Brep2);

  binit_kernel<<<1, 128, 0, stream>>>(btail);
  bin_kernel<<<BIN_BLOCKS, 256, 0, stream>>>(erow, ecol, ew, btail, pack1);
  bucket_finalize_kernel<<<NB, 256, 0, stream>>>(btail, pack1, rowptr, pack2);

  fused_spmm_kan_kernel<0><<<fgrid, 256, 0, stream>>>(
      rowptr, pack2, h0, Brep1, h1, nullptr);
  fused_spmm_kan_kernel<1><<<fgrid, 256, 0, stream>>>(
      rowptr, pack2, h1, Brep2, out, Wout);
}